// Round 3
// baseline (4886.407 us; speedup 1.0000x reference)
//
#include <hip/hip_runtime.h>
#include <math.h>

namespace {

constexpr int N_ = 128, V_ = 25, T_ = 64, C_ = 64, S_ = 3, TS_ = 2;

__device__ __forceinline__ float gelu_f(float x) {
  return 0.5f * x * (1.0f + erff(x * 0.7071067811865475f));
}

// ---------------------------------------------------------------------------
// Generic row-major GEMM: C[204800 x NC] = A[204800 x KT] @ B[KT x NC] + bias
// 128 rows per block, K chunked by 64. LDS pad 68 floats (float4 stride 17,
// odd -> bank starts spread mod 8, <=2-way conflicts).
// ---------------------------------------------------------------------------
template <int KT, int NC>
__launch_bounds__(256, 2)
__global__ void gemm_bias(const float* __restrict__ A, const float* __restrict__ B,
                          const float* __restrict__ bias, float* __restrict__ C) {
  constexpr int NJ = NC / 16;
  __shared__ float Al[128 * 68];
  __shared__ float Bl[NC * 68];
  const int tid = threadIdx.x;
  const int ri = tid >> 4;   // 0..15
  const int ci = tid & 15;   // 0..15
  const int row0 = blockIdx.x * 128;
  float acc[8][NJ];
#pragma unroll
  for (int i = 0; i < 8; ++i)
#pragma unroll
    for (int j = 0; j < NJ; ++j) acc[i][j] = 0.f;

  for (int kc = 0; kc < KT / 64; ++kc) {
#pragma unroll
    for (int m = 0; m < 8; ++m) {
      int idx = m * 256 + tid;
      int row = idx >> 4, kq = idx & 15;
      float4 v = *(const float4*)&A[(row0 + row) * KT + kc * 64 + kq * 4];
      *(float4*)&Al[row * 68 + kq * 4] = v;
    }
#pragma unroll
    for (int m = 0; m < (64 * NC) / 256; ++m) {
      int idx = m * 256 + tid;
      int k = idx / NC, c = idx % NC;
      Bl[c * 68 + k] = B[(kc * 64 + k) * NC + c];
    }
    __syncthreads();
#pragma unroll
    for (int k4 = 0; k4 < 16; ++k4) {
      float4 av[8], bv[NJ];
#pragma unroll
      for (int i = 0; i < 8; ++i)
        av[i] = *(const float4*)&Al[(ri + 16 * i) * 68 + k4 * 4];
#pragma unroll
      for (int j = 0; j < NJ; ++j)
        bv[j] = *(const float4*)&Bl[(ci + 16 * j) * 68 + k4 * 4];
#pragma unroll
      for (int i = 0; i < 8; ++i)
#pragma unroll
        for (int j = 0; j < NJ; ++j)
          acc[i][j] += av[i].x * bv[j].x + av[i].y * bv[j].y +
                       av[i].z * bv[j].z + av[i].w * bv[j].w;
    }
    __syncthreads();
  }
#pragma unroll
  for (int j = 0; j < NJ; ++j) {
    float b = bias[ci + 16 * j];
#pragma unroll
    for (int i = 0; i < 8; ++i)
      C[(row0 + ri + 16 * i) * NC + ci + 16 * j] = acc[i][j] + b;
  }
}

// ---------------------------------------------------------------------------
// Spatial attention scores: att[n,u,v,s] = tanh(sum_{t,c} q k /1024)*alpha+att0
// qk layout (N,V,T,96), q at c*6+s, k at c*6+3+s. Block per (n,u).
// ---------------------------------------------------------------------------
__global__ void att_s_kernel(const float* __restrict__ qk, const float* __restrict__ alphas,
                             const float* __restrict__ att0, float* __restrict__ att) {
  __shared__ float lq[T_ * 96];  // full qk row for u (24 KB)
  const int b = blockIdx.x;
  const int n = b / V_, u = b % V_;
  const int tid = threadIdx.x;
  const float* qrow = qk + (n * V_ + u) * T_ * 96;
#pragma unroll
  for (int m = 0; m < 24; ++m) lq[m * 256 + tid] = qrow[m * 256 + tid];
  __syncthreads();
  const int w = tid >> 6, lane = tid & 63;
  for (int v = w; v < V_; v += 4) {
    float a0 = 0.f, a1 = 0.f, a2 = 0.f;
    const float* krow = qk + (n * V_ + v) * T_ * 96 + 3;
    for (int idx = lane; idx < 1024; idx += 64) {
      int t = idx >> 4, c = idx & 15;
      int off = t * 96 + c * 6;
      a0 += lq[off + 0] * krow[off + 0];
      a1 += lq[off + 1] * krow[off + 1];
      a2 += lq[off + 2] * krow[off + 2];
    }
#pragma unroll
    for (int o = 32; o > 0; o >>= 1) {
      a0 += __shfl_down(a0, o);
      a1 += __shfl_down(a1, o);
      a2 += __shfl_down(a2, o);
    }
    if (lane == 0) {
      float* dst = att + ((n * V_ + u) * V_ + v) * S_;
      const float* a0p = att0 + (u * V_ + v) * S_;
      dst[0] = tanhf(a0 * (1.f / 1024.f)) * alphas[0] + a0p[0];
      dst[1] = tanhf(a1 * (1.f / 1024.f)) * alphas[1] + a0p[1];
      dst[2] = tanhf(a2 * (1.f / 1024.f)) * alphas[2] + a0p[2];
    }
  }
}

// ---------------------------------------------------------------------------
// Spatial mix: y1[n,v,t,c*3+s] = sum_u x[n,u,t,c] * att[n,u,v,s]. Block (n,v).
// ---------------------------------------------------------------------------
__global__ void mix_s_kernel(const float* __restrict__ x, const float* __restrict__ att,
                             float* __restrict__ y1) {
  __shared__ float la[V_ * S_];  // 75
  const int b = blockIdx.x;
  const int n = b / V_, v = b % V_;
  const int tid = threadIdx.x;
  if (tid < V_ * S_) {
    int u = tid / 3, s = tid % 3;
    la[tid] = att[((n * V_ + u) * V_ + v) * S_ + s];
  }
  __syncthreads();
  const float* xn = x + n * V_ * T_ * C_;
  float* yrow = y1 + (n * V_ + v) * T_ * 192;
#pragma unroll
  for (int m = 0; m < 16; ++m) {
    int p = m * 256 + tid;
    int t = p >> 6, c = p & 63;
    float a0 = 0.f, a1 = 0.f, a2 = 0.f;
#pragma unroll
    for (int u = 0; u < V_; ++u) {
      float xv = xn[(u * T_ + t) * C_ + c];
      a0 += xv * la[u * 3 + 0];
      a1 += xv * la[u * 3 + 1];
      a2 += xv * la[u * 3 + 2];
    }
    yrow[t * 192 + c * 3 + 0] = a0;
    yrow[t * 192 + c * 3 + 1] = a1;
    yrow[t * 192 + c * 3 + 2] = a2;
  }
}

// ---------------------------------------------------------------------------
// LayerNorm over M elems per block + gelu(resid + ln*g + b).
// TRANSPOSE: M=4096, block=(n,v), write out[n,t,v,c] (for temporal stage).
// ---------------------------------------------------------------------------
template <int M, bool TRANSPOSE>
__global__ void ln_gelu_kernel(const float* __restrict__ in, const float* __restrict__ resid,
                               const float* __restrict__ g, const float* __restrict__ bta,
                               float* __restrict__ out) {
  __shared__ float lv[M];
  __shared__ float red[256];
  const int b = blockIdx.x;
  const int tid = threadIdx.x;
  const float* ip = in + (size_t)b * M;
  float s = 0.f;
  for (int i = tid; i < M; i += 256) {
    float val = ip[i];
    lv[i] = val;
    s += val;
  }
  red[tid] = s;
  __syncthreads();
#pragma unroll
  for (int o = 128; o > 0; o >>= 1) {
    if (tid < o) red[tid] += red[tid + o];
    __syncthreads();
  }
  const float mean = red[0] * (1.f / M);
  __syncthreads();
  float sq = 0.f;
  for (int i = tid; i < M; i += 256) {
    float d = lv[i] - mean;
    sq += d * d;
  }
  red[tid] = sq;
  __syncthreads();
#pragma unroll
  for (int o = 128; o > 0; o >>= 1) {
    if (tid < o) red[tid] += red[tid + o];
    __syncthreads();
  }
  const float inv = rsqrtf(red[0] * (1.f / M) + 1e-5f);
  const float* rp = resid + (size_t)b * M;
  if (!TRANSPOSE) {
    float* op = out + (size_t)b * M;
    for (int i = tid; i < M; i += 256)
      op[i] = gelu_f(rp[i] + (lv[i] - mean) * inv * g[i] + bta[i]);
  } else {
    const int n = b / V_, v = b % V_;
    for (int i = tid; i < M; i += 256) {
      int t = i >> 6, c = i & 63;
      out[((n * T_ + t) * V_ + v) * C_ + c] =
          gelu_f(rp[i] + (lv[i] - mean) * inv * g[i] + bta[i]);
    }
  }
}

// ---------------------------------------------------------------------------
// Temporal attention scores. qkt (N,T,V,128): q_f s0..1, q_b s2..3, k_f s4..5,
// k_b s6..7 at c*8+s. Block per (n,t); streams k rows for each q.
// ---------------------------------------------------------------------------
__global__ void att_t_kernel(const float* __restrict__ qkt, const float* __restrict__ af_al,
                             const float* __restrict__ ab_al, float* __restrict__ att_f,
                             float* __restrict__ att_b) {
  __shared__ float lq[V_ * 128];  // 12.8 KB
  const int b = blockIdx.x;
  const int n = b / T_, t = b % T_;
  const int tid = threadIdx.x;
  const float* qrow = qkt + (size_t)(n * T_ + t) * V_ * 128;
  for (int i = tid; i < V_ * 128; i += 256) lq[i] = qrow[i];
  __syncthreads();
  const int w = tid >> 6, lane = tid & 63;
  for (int q = w; q < T_; q += 4) {
    float f0 = 0.f, f1 = 0.f, b0 = 0.f, b1 = 0.f;
    const float* krow = qkt + (size_t)(n * T_ + q) * V_ * 128;
    for (int idx = lane; idx < 400; idx += 64) {
      int v = idx >> 4, c = idx & 15;
      int off = v * 128 + c * 8;
      float4 kv = *(const float4*)&krow[off + 4];
      f0 += lq[off + 0] * kv.x;
      f1 += lq[off + 1] * kv.y;
      b0 += lq[off + 2] * kv.z;
      b1 += lq[off + 3] * kv.w;
    }
#pragma unroll
    for (int o = 32; o > 0; o >>= 1) {
      f0 += __shfl_down(f0, o);
      f1 += __shfl_down(f1, o);
      b0 += __shfl_down(b0, o);
      b1 += __shfl_down(b1, o);
    }
    if (lane == 0) {
      float maskf = (q <= t) ? 1.f : 0.f;  // fmask = triu^T
      float maskb = (q >= t) ? 1.f : 0.f;  // bmask = triu
      int o = ((n * T_ + t) * T_ + q) * TS_;
      att_f[o + 0] = tanhf(f0 * (1.f / 400.f)) * af_al[0] * maskf;
      att_f[o + 1] = tanhf(f1 * (1.f / 400.f)) * af_al[1] * maskf;
      att_b[o + 0] = tanhf(b0 * (1.f / 400.f)) * ab_al[0] * maskb;
      att_b[o + 1] = tanhf(b1 * (1.f / 400.f)) * ab_al[1] * maskb;
    }
  }
}

// ---------------------------------------------------------------------------
// Temporal mix: z[n,q,v,c*2+s](f) / +128 (b) = sum_t y[n,t,v,c]*att_{f,b}[n,t,q,s]
// Block = (n, qc<8 of 8 q's, vcc<4 of 512 (v,c) cols); 2 cols/thread.
// ---------------------------------------------------------------------------
__launch_bounds__(256, 2)
__global__ void mix_t_kernel(const float* __restrict__ yt, const float* __restrict__ att_f,
                             const float* __restrict__ att_b, float* __restrict__ z) {
  __shared__ float laf[1024], lab[1024];  // [t][qi*2+s]
  const int b = blockIdx.x;
  const int n = b >> 5;
  const int qc = (b & 31) >> 2, vcc = b & 3;
  const int tid = threadIdx.x;
#pragma unroll
  for (int m = 0; m < 4; ++m) {
    int idx = m * 256 + tid;
    int t = idx >> 4, rr = idx & 15;
    laf[idx] = att_f[(size_t)(n * T_ + t) * T_ * TS_ + qc * 16 + rr];
    lab[idx] = att_b[(size_t)(n * T_ + t) * T_ * TS_ + qc * 16 + rr];
  }
  __syncthreads();
  const int vc0 = vcc * 512 + tid, vc1 = vc0 + 256;
  const bool va0 = vc0 < 1600, va1 = vc1 < 1600;
  float accf0[16], accf1[16], accb0[16], accb1[16];
#pragma unroll
  for (int i = 0; i < 16; ++i) accf0[i] = accf1[i] = accb0[i] = accb1[i] = 0.f;
  for (int t = 0; t < T_; ++t) {
    const float* yrow = yt + (size_t)(n * T_ + t) * 1600;
    float y0 = va0 ? yrow[vc0] : 0.f;
    float y1v = va1 ? yrow[vc1] : 0.f;
#pragma unroll
    for (int q4 = 0; q4 < 4; ++q4) {
      float4 af = *(const float4*)&laf[t * 16 + q4 * 4];
      float4 ab = *(const float4*)&lab[t * 16 + q4 * 4];
      accf0[q4 * 4 + 0] += y0 * af.x;  accf0[q4 * 4 + 1] += y0 * af.y;
      accf0[q4 * 4 + 2] += y0 * af.z;  accf0[q4 * 4 + 3] += y0 * af.w;
      accf1[q4 * 4 + 0] += y1v * af.x; accf1[q4 * 4 + 1] += y1v * af.y;
      accf1[q4 * 4 + 2] += y1v * af.z; accf1[q4 * 4 + 3] += y1v * af.w;
      accb0[q4 * 4 + 0] += y0 * ab.x;  accb0[q4 * 4 + 1] += y0 * ab.y;
      accb0[q4 * 4 + 2] += y0 * ab.z;  accb0[q4 * 4 + 3] += y0 * ab.w;
      accb1[q4 * 4 + 0] += y1v * ab.x; accb1[q4 * 4 + 1] += y1v * ab.y;
      accb1[q4 * 4 + 2] += y1v * ab.z; accb1[q4 * 4 + 3] += y1v * ab.w;
    }
  }
  if (va0) {
    int v = vc0 >> 6, c = vc0 & 63;
#pragma unroll
    for (int qi = 0; qi < 8; ++qi) {
      int q = qc * 8 + qi;
      float* zp = z + (size_t)((n * T_ + q) * V_ + v) * 256;
      zp[c * 2 + 0] = accf0[qi * 2 + 0];
      zp[c * 2 + 1] = accf0[qi * 2 + 1];
      zp[128 + c * 2 + 0] = accb0[qi * 2 + 0];
      zp[128 + c * 2 + 1] = accb0[qi * 2 + 1];
    }
  }
  if (va1) {
    int v = vc1 >> 6, c = vc1 & 63;
#pragma unroll
    for (int qi = 0; qi < 8; ++qi) {
      int q = qc * 8 + qi;
      float* zp = z + (size_t)((n * T_ + q) * V_ + v) * 256;
      zp[c * 2 + 0] = accf1[qi * 2 + 0];
      zp[c * 2 + 1] = accf1[qi * 2 + 1];
      zp[128 + c * 2 + 0] = accb1[qi * 2 + 0];
      zp[128 + c * 2 + 1] = accb1[qi * 2 + 1];
    }
  }
}

// conv weight transpose: wT[(dt*64+c)*64+c'] = w[(c'*64+c)*7+dt]
__global__ void convw_transpose(const float* __restrict__ w, float* __restrict__ wT) {
  int idx = blockIdx.x * 256 + threadIdx.x;
  if (idx < 64 * 64 * 7) {
    int dt = idx % 7, c = (idx / 7) % 64, cp = idx / 448;
    wT[(dt * 64 + c) * 64 + cp] = w[idx];
  }
}

// ---------------------------------------------------------------------------
// Conv 7x1 along T + bias, block per (n,t); also per-block BN partial sums.
// z1 layout (N,T,V,C). Thread = (vg = tid>>6, c' = tid&63), 6-7 v's each.
// ---------------------------------------------------------------------------
__launch_bounds__(256, 2)
__global__ void conv_kernel(const float* __restrict__ zf, const float* __restrict__ wT,
                            const float* __restrict__ cb, float* __restrict__ z1,
                            float* __restrict__ part) {
  __shared__ float lz[7 * 1600];   // 44.8 KB
  __shared__ float lw[64 * 68];    // 17.4 KB, [c'][c]
  __shared__ float red[256], red2[256];
  const int b = blockIdx.x;
  const int n = b / T_, t = b % T_;
  const int tid = threadIdx.x;
  for (int idx = tid; idx < 7 * 1600; idx += 256) {
    int dt = idx / 1600, r = idx - dt * 1600;
    int tt = t + dt - 3;
    lz[idx] = (tt >= 0 && tt < T_) ? zf[(size_t)(n * T_ + tt) * 1600 + r] : 0.f;
  }
  const int cp = tid & 63, vg = tid >> 6;
  float acc[7];
#pragma unroll
  for (int vi = 0; vi < 7; ++vi) acc[vi] = cb[cp];
  const int nvi = (vg == 0) ? 7 : 6;  // v = vg + 4*vi < 25
  for (int dt = 0; dt < 7; ++dt) {
    __syncthreads();
    for (int idx = tid; idx < 4096; idx += 256) {
      int c = idx >> 6, cc = idx & 63;
      lw[cc * 68 + c] = wT[(dt * 64 + c) * 64 + cc];
    }
    __syncthreads();
#pragma unroll
    for (int c4 = 0; c4 < 16; ++c4) {
      float4 wv = *(const float4*)&lw[cp * 68 + c4 * 4];
#pragma unroll
      for (int vi = 0; vi < 7; ++vi) {
        int v = vg + 4 * vi;
        if (v < V_) {
          float4 zv = *(const float4*)&lz[dt * 1600 + v * 64 + c4 * 4];
          acc[vi] += wv.x * zv.x + wv.y * zv.y + wv.z * zv.z + wv.w * zv.w;
        }
      }
    }
  }
  float lsum = 0.f, lsq = 0.f;
  for (int vi = 0; vi < nvi; ++vi) {
    int v = vg + 4 * vi;
    z1[(size_t)((n * T_ + t) * V_ + v) * C_ + cp] = acc[vi];
    lsum += acc[vi];
    lsq += acc[vi] * acc[vi];
  }
  red[tid] = lsum;
  red2[tid] = lsq;
  __syncthreads();
  if (tid < 64) {
    float s = red[tid] + red[tid + 64] + red[tid + 128] + red[tid + 192];
    float q = red2[tid] + red2[tid + 64] + red2[tid + 128] + red2[tid + 192];
    part[(size_t)b * 128 + tid] = s;
    part[(size_t)b * 128 + 64 + tid] = q;
  }
}

// Per-channel BN stats -> scale/shift. One block per channel.
__global__ void bn_final(const float* __restrict__ part, const float* __restrict__ g,
                         const float* __restrict__ bb, float* __restrict__ sc) {
  __shared__ float red[256], red2[256];
  const int c = blockIdx.x;
  const int tid = threadIdx.x;
  float s = 0.f, q = 0.f;
  for (int i = tid; i < 8192; i += 256) {
    s += part[(size_t)i * 128 + c];
    q += part[(size_t)i * 128 + 64 + c];
  }
  red[tid] = s;
  red2[tid] = q;
  __syncthreads();
#pragma unroll
  for (int o = 128; o > 0; o >>= 1) {
    if (tid < o) {
      red[tid] += red[tid + o];
      red2[tid] += red2[tid + o];
    }
    __syncthreads();
  }
  if (tid == 0) {
    const float M = 204800.f;
    float mean = red[0] / M;
    float var = red2[0] / M - mean * mean;
    float scale = g[c] * rsqrtf(var + 1e-5f);
    sc[c] = scale;
    sc[64 + c] = bb[c] - mean * scale;
  }
}

// out[n,v,t,c] = gelu(zf[n,t,v,c] + z1[n,t,v,c]*scale[c] + shift[c])
__global__ void final_kernel(const float* __restrict__ zf, const float* __restrict__ z1,
                             const float* __restrict__ sc, float* __restrict__ out) {
  const int b = blockIdx.x;
  const int n = b / T_, t = b % T_;
  const int tid = threadIdx.x;
  const size_t base = (size_t)(n * T_ + t) * 1600;
  for (int i = tid; i < 1600; i += 256) {
    int v = i >> 6, c = i & 63;
    float val = zf[base + i] + z1[base + i] * sc[c] + sc[64 + c];
    out[(size_t)((n * V_ + v) * T_ + t) * C_ + c] = gelu_f(val);
  }
}

}  // namespace

extern "C" void kernel_launch(void* const* d_in, const int* in_sizes, int n_in,
                              void* d_out, int out_size, void* d_ws, size_t ws_size,
                              hipStream_t stream) {
  (void)in_sizes; (void)n_in; (void)out_size; (void)ws_size;
  const float* x          = (const float*)d_in[0];
  const float* w_in_s     = (const float*)d_in[1];
  const float* b_in_s     = (const float*)d_in[2];
  const float* alphas     = (const float*)d_in[3];
  const float* att0s      = (const float*)d_in[4];
  const float* w_out_s    = (const float*)d_in[5];
  const float* b_out_s    = (const float*)d_in[6];
  const float* ln_out_s_g = (const float*)d_in[7];
  const float* ln_out_s_b = (const float*)d_in[8];
  const float* w_ff_s     = (const float*)d_in[9];
  const float* b_ff_s     = (const float*)d_in[10];
  const float* ln_ff_s_g  = (const float*)d_in[11];
  const float* ln_ff_s_b  = (const float*)d_in[12];
  const float* w_in_t     = (const float*)d_in[13];
  const float* b_in_t     = (const float*)d_in[14];
  const float* alphat_f   = (const float*)d_in[15];
  const float* alphat_b   = (const float*)d_in[16];
  const float* w_out_t    = (const float*)d_in[17];
  const float* b_out_t    = (const float*)d_in[18];
  const float* ln_out_t_g = (const float*)d_in[19];
  const float* ln_out_t_b = (const float*)d_in[20];
  const float* w_ff_t     = (const float*)d_in[21];
  const float* b_ff_t     = (const float*)d_in[22];
  const float* ln_ff_t_g  = (const float*)d_in[23];
  const float* ln_ff_t_b  = (const float*)d_in[24];
  const float* conv_w     = (const float*)d_in[25];
  const float* conv_b     = (const float*)d_in[26];
  const float* bn_g       = (const float*)d_in[27];
  const float* bn_b       = (const float*)d_in[28];
  float* out = (float*)d_out;
  float* ws = (float*)d_ws;

  // -------------------------------------------------------------------------
  // Tight workspace aliasing. d_ws requirement: 65,536,000 floats = 262.1 MB.
  // Big slot Z (52,428,800 fl) rotates qk -> y1 -> qkt -> z, with 13.1M-float
  // sub-slots Z0..Z3 for the small intermediates when z/qk/y1 are dead.
  // Slot Y (13,107,200 fl) holds yt (live steps 7-14), then z1b.
  // d_out doubles as scratch for att_s / att_f+att_b / z2 (all dead before
  // final_kernel writes the real output).
  // Liveness audit (step: reads -> writes):
  //  1 gemm:   x -> qk@Z0-Z1          2 att_s: qk -> att_s@OUT
  //  3 mix_s:  x,att_s -> y1@Z0-Z2    4 gemm:  y1 -> y2@Z3
  //  5 ln:     y2,x -> y5@Z0          6 gemm:  y5 -> y6@Z1
  //  7 lnT:    y6,x -> yt@Y           8 gemm:  yt -> qkt@Z0-Z1
  //  9 att_t:  qkt -> attf/attb@OUT  10 mix_t: yt,att -> z@Z0-Z3
  // 11 gemm:   z -> z2@OUT           12 ln:    z2,yt -> z5@Z0
  // 13 gemm:   z5 -> z6@Z1           14 ln:    z6,yt -> zf@Z2
  // 15 wT@Z0                         16 conv:  zf,wT -> z1b@Y, part@Z1
  // 17 bn:     part -> bnsc@Z3       18 final: zf,z1b,bnsc -> out@OUT
  // -------------------------------------------------------------------------
  const size_t Z0 = 0;
  const size_t Z1 = 13107200;
  const size_t Z2 = 26214400;
  const size_t Z3 = 39321600;
  const size_t Ys = 52428800;

  float* qk    = ws + Z0;      // 19,660,800 (spans Z0-Z1)
  float* y1    = ws + Z0;      // 39,321,600 (spans Z0-Z2)
  float* y2    = ws + Z3;      // 13,107,200
  float* y5    = ws + Z0;
  float* y6    = ws + Z1;
  float* yt    = ws + Ys;      // 13,107,200, live 7-14
  float* qkt   = ws + Z0;      // 26,214,400 (spans Z0-Z1)
  float* z     = ws + Z0;      // 52,428,800 (spans Z0-Z3)
  float* z5    = ws + Z0;
  float* z6    = ws + Z1;
  float* zf    = ws + Z2;
  float* wT    = ws + Z0;      // 28,672
  float* part  = ws + Z1;      // 1,048,576
  float* bnsc  = ws + Z3;      // 128
  float* z1b   = ws + Ys;      // 13,107,200 (yt dead)

  float* att_s = out;                 // 240,000   (dead after step 3)
  float* att_f = out;                 // 1,048,576 (dead after step 10)
  float* att_b = out + 1048576;       // 1,048,576 (dead after step 10)
  float* z2    = out;                 // 13,107,200 (dead after step 12)

  dim3 blk(256);
  // ---- spatial stage ----
  gemm_bias<64, 96><<<1600, blk, 0, stream>>>(x, w_in_s, b_in_s, qk);
  att_s_kernel<<<3200, blk, 0, stream>>>(qk, alphas, att0s, att_s);
  mix_s_kernel<<<3200, blk, 0, stream>>>(x, att_s, y1);
  gemm_bias<192, 64><<<1600, blk, 0, stream>>>(y1, w_out_s, b_out_s, y2);
  ln_gelu_kernel<4096, false><<<3200, blk, 0, stream>>>(y2, x, ln_out_s_g, ln_out_s_b, y5);
  gemm_bias<64, 64><<<1600, blk, 0, stream>>>(y5, w_ff_s, b_ff_s, y6);
  ln_gelu_kernel<4096, true><<<3200, blk, 0, stream>>>(y6, x, ln_ff_s_g, ln_ff_s_b, yt);
  // ---- temporal stage ----
  gemm_bias<64, 128><<<1600, blk, 0, stream>>>(yt, w_in_t, b_in_t, qkt);
  att_t_kernel<<<8192, blk, 0, stream>>>(qkt, alphat_f, alphat_b, att_f, att_b);
  mix_t_kernel<<<4096, blk, 0, stream>>>(yt, att_f, att_b, z);
  gemm_bias<256, 64><<<1600, blk, 0, stream>>>(z, w_out_t, b_out_t, z2);
  ln_gelu_kernel<1600, false><<<8192, blk, 0, stream>>>(z2, yt, ln_out_t_g, ln_out_t_b, z5);
  gemm_bias<64, 64><<<1600, blk, 0, stream>>>(z5, w_ff_t, b_ff_t, z6);
  ln_gelu_kernel<1600, false><<<8192, blk, 0, stream>>>(z6, yt, ln_ff_t_g, ln_ff_t_b, zf);
  // ---- conv + BN + output ----
  convw_transpose<<<112, blk, 0, stream>>>(conv_w, wT);
  conv_kernel<<<8192, blk, 0, stream>>>(zf, wT, conv_b, z1b, part);
  bn_final<<<64, blk, 0, stream>>>(part, bn_g, bn_b, bnsc);
  final_kernel<<<8192, blk, 0, stream>>>(zf, z1b, bnsc, out);
}

// Round 4
// 3197.893 us; speedup vs baseline: 1.5280x; 1.5280x over previous
//
#include <hip/hip_runtime.h>
#include <math.h>

namespace {

constexpr int V_ = 25, T_ = 64, C_ = 64;

__device__ __forceinline__ float gelu_f(float x) {
  return 0.5f * x * (1.0f + erff(x * 0.7071067811865475f));
}

__device__ __forceinline__ float block_sum(float v, float* red, int tid) {
  red[tid] = v; __syncthreads();
#pragma unroll
  for (int o = 128; o > 0; o >>= 1) {
    if (tid < o) red[tid] += red[tid + o];
    __syncthreads();
  }
  float r = red[0]; __syncthreads();
  return r;
}

// ---------------------------------------------------------------------------
// K=64 GEMM: C[204800 x NC] = A[204800 x 64] @ B[64 x NC] + bias.
// 64 rows/block; thread = 8 rows x float4 cols; ~90 VGPRs (no spill).
// ---------------------------------------------------------------------------
template <int NC>
__launch_bounds__(256, 2)
__global__ void gemm_k64(const float* __restrict__ A, const float* __restrict__ B,
                         const float* __restrict__ bias, float* __restrict__ C) {
  __shared__ float Al[64 * 68];
  __shared__ float Bl[64 * (NC + 4)];
  const int tid = threadIdx.x;
  const int row0 = blockIdx.x * 64;
  for (int i = tid; i < 4096; i += 256)
    Al[(i >> 6) * 68 + (i & 63)] = A[(size_t)(row0 + (i >> 6)) * 64 + (i & 63)];
  for (int i = tid; i < 64 * NC; i += 256) {
    int k = i / NC, c = i - k * NC;
    Bl[k * (NC + 4) + c] = B[i];
  }
  __syncthreads();
  const int ri = tid >> 5, cg = tid & 31;
  if (cg * 4 < NC) {
    float4 acc[8];
    float4 bf = *(const float4*)&bias[cg * 4];
#pragma unroll
    for (int i = 0; i < 8; ++i) acc[i] = bf;
    for (int k0 = 0; k0 < 64; k0 += 4) {
      float4 bv0 = *(const float4*)&Bl[(k0 + 0) * (NC + 4) + cg * 4];
      float4 bv1 = *(const float4*)&Bl[(k0 + 1) * (NC + 4) + cg * 4];
      float4 bv2 = *(const float4*)&Bl[(k0 + 2) * (NC + 4) + cg * 4];
      float4 bv3 = *(const float4*)&Bl[(k0 + 3) * (NC + 4) + cg * 4];
#pragma unroll
      for (int i = 0; i < 8; ++i) {
        float4 av = *(const float4*)&Al[(ri * 8 + i) * 68 + k0];
        acc[i].x += av.x * bv0.x + av.y * bv1.x + av.z * bv2.x + av.w * bv3.x;
        acc[i].y += av.x * bv0.y + av.y * bv1.y + av.z * bv2.y + av.w * bv3.y;
        acc[i].z += av.x * bv0.z + av.y * bv1.z + av.z * bv2.z + av.w * bv3.z;
        acc[i].w += av.x * bv0.w + av.y * bv1.w + av.z * bv2.w + av.w * bv3.w;
      }
    }
#pragma unroll
    for (int i = 0; i < 8; ++i)
      *(float4*)&C[(size_t)(row0 + ri * 8 + i) * NC + cg * 4] = acc[i];
  }
}

// ---------------------------------------------------------------------------
// Spatial attention scores. Block = (n, u-quad); wave = one u; Q staged once,
// K rows staged per v. att[n,u,v,s] = tanh(dot/1024)*alpha[s] + att0[u,v,s].
// ---------------------------------------------------------------------------
__global__ void att_s_kernel(const float* __restrict__ qk, const float* __restrict__ alphas,
                             const float* __restrict__ att0, float* __restrict__ att) {
  __shared__ float qs[4 * 3072];  // [u][s][1024]
  __shared__ float ks[3072];
  const int b = blockIdx.x, tid = threadIdx.x;
  const int n = b / 7, ug = b % 7;
  const int u0 = ug * 4;
  const int nu = (25 - u0 < 4) ? (25 - u0) : 4;
  for (int i = tid; i < nu * 3072; i += 256) {
    int ul = i / 3072, r = i - ul * 3072;
    int s = r >> 10, idx = r & 1023, t = idx >> 4, c = idx & 15;
    qs[i] = qk[(size_t)(n * 25 + u0 + ul) * 6144 + t * 96 + c * 6 + s];
  }
  const int ui = tid >> 6, l = tid & 63;
  const int u = u0 + ui;
  const float a0 = alphas[0], a1 = alphas[1], a2 = alphas[2];
  for (int v = 0; v < 25; ++v) {
    __syncthreads();
    for (int i = tid; i < 3072; i += 256) {
      int s = i >> 10, idx = i & 1023, t = idx >> 4, c = idx & 15;
      ks[i] = qk[(size_t)(n * 25 + v) * 6144 + t * 96 + c * 6 + 3 + s];
    }
    __syncthreads();
    if (u < 25) {
      float s0 = 0.f, s1 = 0.f, s2 = 0.f;
      for (int idx = l; idx < 1024; idx += 64) {
        s0 += qs[ui * 3072 + idx] * ks[idx];
        s1 += qs[ui * 3072 + 1024 + idx] * ks[1024 + idx];
        s2 += qs[ui * 3072 + 2048 + idx] * ks[2048 + idx];
      }
#pragma unroll
      for (int o = 32; o > 0; o >>= 1) {
        s0 += __shfl_down(s0, o);
        s1 += __shfl_down(s1, o);
        s2 += __shfl_down(s2, o);
      }
      if (l == 0) {
        float* dst = &att[(size_t)((n * 25 + u) * 25 + v) * 3];
        const float* ap = &att0[(u * 25 + v) * 3];
        dst[0] = tanhf(s0 * (1.f / 1024.f)) * a0 + ap[0];
        dst[1] = tanhf(s1 * (1.f / 1024.f)) * a1 + ap[1];
        dst[2] = tanhf(s2 * (1.f / 1024.f)) * a2 + ap[2];
      }
    }
  }
}

// ---------------------------------------------------------------------------
// Fused spatial mix + out-projection. Block (n,t):
// y1[v][c*3+s] = sum_u x[n,u,t,c] att[n,u,v,s]; y2 = y1 @ w_out_s + b.
// ---------------------------------------------------------------------------
__launch_bounds__(256, 2)
__global__ void mix_gemm_s(const float* __restrict__ x, const float* __restrict__ att,
                           const float* __restrict__ w, const float* __restrict__ bias,
                           float* __restrict__ y2) {
  __shared__ float la[1875];
  __shared__ float xs[1600];        // [u][c]
  __shared__ float y1l[25 * 194];   // [v][192] pad
  __shared__ float wl[192 * 36];    // half cols, pad 36 (16B aligned)
  const int b = blockIdx.x, tid = threadIdx.x;
  const int n = b >> 6, t = b & 63;
  for (int i = tid; i < 1875; i += 256) la[i] = att[(size_t)n * 1875 + i];
  for (int i = tid; i < 1600; i += 256) {
    int u = i >> 6, c = i & 63;
    xs[i] = x[(size_t)((n * 25 + u) * 64 + t) * 64 + c];
  }
  __syncthreads();
  for (int slot = tid; slot < 400; slot += 256) {
    int v = slot >> 4, cg = slot & 15;
    float4 s0 = {0, 0, 0, 0}, s1 = {0, 0, 0, 0}, s2 = {0, 0, 0, 0};
    for (int u = 0; u < 25; ++u) {
      float4 xv = *(const float4*)&xs[u * 64 + cg * 4];
      const float* lp = &la[(u * 25 + v) * 3];
      float w0 = lp[0], w1 = lp[1], w2 = lp[2];
      s0.x += xv.x * w0; s0.y += xv.y * w0; s0.z += xv.z * w0; s0.w += xv.w * w0;
      s1.x += xv.x * w1; s1.y += xv.y * w1; s1.z += xv.z * w1; s1.w += xv.w * w1;
      s2.x += xv.x * w2; s2.y += xv.y * w2; s2.z += xv.z * w2; s2.w += xv.w * w2;
    }
    float* yp = &y1l[v * 194 + cg * 12];
    yp[0] = s0.x; yp[1] = s1.x; yp[2] = s2.x;
    yp[3] = s0.y; yp[4] = s1.y; yp[5] = s2.y;
    yp[6] = s0.z; yp[7] = s1.z; yp[8] = s2.z;
    yp[9] = s0.w; yp[10] = s1.w; yp[11] = s2.w;
  }
  for (int h = 0; h < 2; ++h) {
    __syncthreads();
    for (int i = tid; i < 192 * 32; i += 256) {
      int k = i >> 5, cc = i & 31;
      wl[k * 36 + cc] = w[k * 64 + h * 32 + cc];
    }
    __syncthreads();
    if (tid < 200) {
      int v = tid >> 3, cp = tid & 7;
      float4 acc = *(const float4*)&bias[h * 32 + cp * 4];
      for (int k = 0; k < 192; ++k) {
        float yv = y1l[v * 194 + k];
        float4 wv = *(const float4*)&wl[k * 36 + cp * 4];
        acc.x += yv * wv.x; acc.y += yv * wv.y; acc.z += yv * wv.z; acc.w += yv * wv.w;
      }
      *(float4*)&y2[(size_t)((n * 25 + v) * 64 + t) * 64 + h * 32 + cp * 4] = acc;
    }
  }
}

// ---------------------------------------------------------------------------
// Fused LN -> gelu(x+.) -> @w_ff -> LN -> gelu(x+.) for spatial stage.
// Block = one (n,v) LN group of 64x64; writes yt transposed (n,t,v,c).
// ---------------------------------------------------------------------------
__global__ void lnln_s_kernel(const float* __restrict__ y2, const float* __restrict__ x,
                              const float* __restrict__ wff, const float* __restrict__ bff,
                              const float* __restrict__ g1, const float* __restrict__ b1,
                              const float* __restrict__ g2, const float* __restrict__ b2,
                              float* __restrict__ yt) {
  __shared__ float ya[64 * 66];
  __shared__ float wl[64 * 68];
  __shared__ float y6l[64 * 68];
  __shared__ float red[256];
  const int g = blockIdx.x, tid = threadIdx.x;
  const int n = g / 25, v = g % 25;
  const size_t base = (size_t)g * 4096;
  float s = 0.f;
  for (int i = tid; i < 4096; i += 256) {
    float val = y2[base + i];
    ya[(i >> 6) * 66 + (i & 63)] = val;
    s += val;
  }
  for (int i = tid; i < 4096; i += 256) wl[(i >> 6) * 68 + (i & 63)] = wff[i];
  float mean = block_sum(s, red, tid) * (1.f / 4096.f);
  float sq = 0.f;
  for (int i = tid; i < 4096; i += 256) {
    float d = ya[(i >> 6) * 66 + (i & 63)] - mean;
    sq += d * d;
  }
  float inv = rsqrtf(block_sum(sq, red, tid) * (1.f / 4096.f) + 1e-5f);
  for (int i = tid; i < 4096; i += 256) {
    int o = (i >> 6) * 66 + (i & 63);
    ya[o] = gelu_f(x[base + i] + (ya[o] - mean) * inv * g1[i] + b1[i]);
  }
  __syncthreads();
  const int ri = tid >> 4, ci = tid & 15;
  {
    float4 bf = *(const float4*)&bff[ci * 4];
    float4 acc[4];
#pragma unroll
    for (int i = 0; i < 4; ++i) acc[i] = bf;
    for (int k = 0; k < 64; ++k) {
      float4 wv = *(const float4*)&wl[k * 68 + ci * 4];
#pragma unroll
      for (int i = 0; i < 4; ++i) {
        float av = ya[(ri + 16 * i) * 66 + k];
        acc[i].x += av * wv.x; acc[i].y += av * wv.y;
        acc[i].z += av * wv.z; acc[i].w += av * wv.w;
      }
    }
#pragma unroll
    for (int i = 0; i < 4; ++i)
      *(float4*)&y6l[(ri + 16 * i) * 68 + ci * 4] = acc[i];
  }
  __syncthreads();
  float s2 = 0.f;
  for (int i = tid; i < 4096; i += 256) s2 += y6l[(i >> 6) * 68 + (i & 63)];
  float mean2 = block_sum(s2, red, tid) * (1.f / 4096.f);
  float sq2 = 0.f;
  for (int i = tid; i < 4096; i += 256) {
    float d = y6l[(i >> 6) * 68 + (i & 63)] - mean2;
    sq2 += d * d;
  }
  float inv2 = rsqrtf(block_sum(sq2, red, tid) * (1.f / 4096.f) + 1e-5f);
  for (int i = tid; i < 4096; i += 256) {
    int t = i >> 6, c = i & 63;
    yt[(size_t)((n * 64 + t) * 25 + v) * 64 + c] =
        gelu_f(x[base + i] + (y6l[t * 68 + c] - mean2) * inv2 * g2[i] + b2[i]);
  }
}

// ---------------------------------------------------------------------------
// Temporal attention scores. Block = (n, t-oct); Q staged once, K per q.
// att4[n][sdi][t][q], sdi = {f0,f1,b0,b1}, tanh/alpha/mask folded.
// ---------------------------------------------------------------------------
__global__ void att_t_kernel(const float* __restrict__ qkt, const float* __restrict__ af_al,
                             const float* __restrict__ ab_al, float* __restrict__ att4) {
  __shared__ float qs[8 * 1600];
  __shared__ float ks[1600];
  const int b = blockIdx.x, tid = threadIdx.x;
  const int n = b >> 3, to = b & 7;
  for (int i = tid; i < 8 * 1600; i += 256) {
    int tt = i / 1600, r = i - tt * 1600;
    int pair = r >> 2, j = r & 3, v = pair >> 4, c = pair & 15;
    qs[i] = qkt[(size_t)((n * 64 + to * 8 + tt) * 25 + v) * 128 + c * 8 + j];
  }
  const int tt = tid >> 5, l = tid & 31;
  const int t = to * 8 + tt;
  const float af0 = af_al[0], af1 = af_al[1], ab0 = ab_al[0], ab1 = ab_al[1];
  for (int q = 0; q < 64; ++q) {
    __syncthreads();
    for (int i = tid; i < 1600; i += 256) {
      int pair = i >> 2, j = i & 3, v = pair >> 4, c = pair & 15;
      ks[i] = qkt[(size_t)((n * 64 + q) * 25 + v) * 128 + c * 8 + 4 + j];
    }
    __syncthreads();
    float f0 = 0.f, f1 = 0.f, b0 = 0.f, b1 = 0.f;
    for (int idx = l; idx < 400; idx += 32) {
      float4 q4 = *(const float4*)&qs[tt * 1600 + idx * 4];
      float4 k4 = *(const float4*)&ks[idx * 4];
      f0 += q4.x * k4.x; f1 += q4.y * k4.y;
      b0 += q4.z * k4.z; b1 += q4.w * k4.w;
    }
#pragma unroll
    for (int o = 16; o > 0; o >>= 1) {
      f0 += __shfl_down(f0, o, 32); f1 += __shfl_down(f1, o, 32);
      b0 += __shfl_down(b0, o, 32); b1 += __shfl_down(b1, o, 32);
    }
    if (l == 0) {
      float mf = (q <= t) ? 1.f : 0.f;
      float mb = (q >= t) ? 1.f : 0.f;
      size_t o4 = ((size_t)(n * 4 + 0) * 64 + t) * 64 + q;
      att4[o4]           = tanhf(f0 * (1.f / 400.f)) * af0 * mf;
      att4[o4 + 4096]    = tanhf(f1 * (1.f / 400.f)) * af1 * mf;
      att4[o4 + 2 * 4096] = tanhf(b0 * (1.f / 400.f)) * ab0 * mb;
      att4[o4 + 3 * 4096] = tanhf(b1 * (1.f / 400.f)) * ab1 * mb;
    }
  }
}

// ---------------------------------------------------------------------------
// Fused temporal mix + out-projection. Block (n, v, q-half of 32):
// zvl[q][col=(dir,c,s)] = sum_t yt[n,t,v,c] att4[n,sdi,t,q]; z2 = zvl@w_out_t.
// zvl overlays as4/ys after a barrier (acc carried in registers).
// ---------------------------------------------------------------------------
__launch_bounds__(256, 2)
__global__ void mix_gemm_t(const float* __restrict__ yt, const float* __restrict__ att4,
                           const float* __restrict__ w, const float* __restrict__ bias,
                           float* __restrict__ z2) {
  __shared__ float smem[12288];  // as4[4][64][32] (8192) + ys[64][64] (4096); zvl overlays
  float* as4 = smem;
  float* ys = smem + 8192;
  float* zvl = smem;             // [32][258]
  const int b = blockIdx.x, tid = threadIdx.x;
  const int n = b / 50, r = b % 50;
  const int v = r >> 1, qh = r & 1;
  const int q0b = qh * 32;
  for (int i = tid; i < 8192; i += 256) {
    int sdi = i >> 11, t = (i >> 5) & 63, qq = i & 31;
    as4[i] = att4[((size_t)(n * 4 + sdi) * 64 + t) * 64 + q0b + qq];
  }
  for (int i = tid; i < 4096; i += 256) {
    int t = i >> 6, c = i & 63;
    ys[i] = yt[(size_t)((n * 64 + t) * 25 + v) * 64 + c];
  }
  __syncthreads();
  const int qg = tid >> 4, cg = tid & 15;
  const int q0 = qg * 2, c0 = cg * 4;
  float4 a00 = {0,0,0,0}, a01 = {0,0,0,0}, a10 = {0,0,0,0}, a11 = {0,0,0,0};
  float4 a20 = {0,0,0,0}, a21 = {0,0,0,0}, a30 = {0,0,0,0}, a31 = {0,0,0,0};
  for (int t = 0; t < 64; ++t) {
    float4 bv = *(const float4*)&ys[t * 64 + c0];
    float2 av0 = *(const float2*)&as4[(0 * 64 + t) * 32 + q0];
    float2 av1 = *(const float2*)&as4[(1 * 64 + t) * 32 + q0];
    float2 av2 = *(const float2*)&as4[(2 * 64 + t) * 32 + q0];
    float2 av3 = *(const float2*)&as4[(3 * 64 + t) * 32 + q0];
#define FMA4S(A, S) A.x += bv.x * (S); A.y += bv.y * (S); A.z += bv.z * (S); A.w += bv.w * (S)
    FMA4S(a00, av0.x); FMA4S(a01, av0.y);
    FMA4S(a10, av1.x); FMA4S(a11, av1.y);
    FMA4S(a20, av2.x); FMA4S(a21, av2.y);
    FMA4S(a30, av3.x); FMA4S(a31, av3.y);
#undef FMA4S
  }
  __syncthreads();  // as4/ys dead; zvl overlays
#define STORE_ZV(A, SDI, QI)                                                     \
  { int cb = ((SDI) >= 2 ? 128 : 0) + ((SDI) & 1);                               \
    float* zp = &zvl[(q0 + (QI)) * 258 + cb];                                    \
    zp[(c0 + 0) * 2] = A.x; zp[(c0 + 1) * 2] = A.y;                              \
    zp[(c0 + 2) * 2] = A.z; zp[(c0 + 3) * 2] = A.w; }
  STORE_ZV(a00, 0, 0); STORE_ZV(a01, 0, 1);
  STORE_ZV(a10, 1, 0); STORE_ZV(a11, 1, 1);
  STORE_ZV(a20, 2, 0); STORE_ZV(a21, 2, 1);
  STORE_ZV(a30, 3, 0); STORE_ZV(a31, 3, 1);
#undef STORE_ZV
  __syncthreads();
  const int qg2 = tid >> 6, cp = tid & 63;
  float acc2[8] = {0, 0, 0, 0, 0, 0, 0, 0};
  for (int col = 0; col < 256; ++col) {
    float wv = w[col * 64 + cp];
#pragma unroll
    for (int qi = 0; qi < 8; ++qi) acc2[qi] += zvl[(qg2 * 8 + qi) * 258 + col] * wv;
  }
  float bb = bias[cp];
#pragma unroll
  for (int qi = 0; qi < 8; ++qi)
    z2[(size_t)((n * 64 + q0b + qg2 * 8 + qi) * 25 + v) * 64 + cp] = acc2[qi] + bb;
}

// ---------------------------------------------------------------------------
// Fused LN -> gelu(y+.) -> @w_ff_t -> LN -> gelu(y+.) for temporal stage.
// Block = one (n,q) LN group of 25x64.
// ---------------------------------------------------------------------------
__global__ void lnln_t_kernel(const float* __restrict__ z2, const float* __restrict__ ytr,
                              const float* __restrict__ wff, const float* __restrict__ bff,
                              const float* __restrict__ g1, const float* __restrict__ b1,
                              const float* __restrict__ g2, const float* __restrict__ b2,
                              float* __restrict__ zf) {
  __shared__ float za[25 * 66];
  __shared__ float yts[25 * 66];
  __shared__ float wl[64 * 68];
  __shared__ float z6l[25 * 68];
  __shared__ float red[256];
  const int g = blockIdx.x, tid = threadIdx.x;
  const size_t base = (size_t)g * 1600;
  float s = 0.f;
  for (int i = tid; i < 1600; i += 256) {
    float val = z2[base + i];
    za[(i >> 6) * 66 + (i & 63)] = val;
    yts[(i >> 6) * 66 + (i & 63)] = ytr[base + i];
    s += val;
  }
  for (int i = tid; i < 4096; i += 256) wl[(i >> 6) * 68 + (i & 63)] = wff[i];
  float mean = block_sum(s, red, tid) * (1.f / 1600.f);
  float sq = 0.f;
  for (int i = tid; i < 1600; i += 256) {
    float d = za[(i >> 6) * 66 + (i & 63)] - mean;
    sq += d * d;
  }
  float inv = rsqrtf(block_sum(sq, red, tid) * (1.f / 1600.f) + 1e-5f);
  for (int i = tid; i < 1600; i += 256) {
    int o = (i >> 6) * 66 + (i & 63);
    za[o] = gelu_f(yts[o] + (za[o] - mean) * inv * g1[i] + b1[i]);
  }
  __syncthreads();
  for (int slot = tid; slot < 400; slot += 256) {
    int v = slot >> 4, cq = slot & 15;
    float4 acc = *(const float4*)&bff[cq * 4];
    for (int k = 0; k < 64; ++k) {
      float av = za[v * 66 + k];
      float4 wv = *(const float4*)&wl[k * 68 + cq * 4];
      acc.x += av * wv.x; acc.y += av * wv.y; acc.z += av * wv.z; acc.w += av * wv.w;
    }
    *(float4*)&z6l[v * 68 + cq * 4] = acc;
  }
  __syncthreads();
  float s2 = 0.f;
  for (int i = tid; i < 1600; i += 256) s2 += z6l[(i >> 6) * 68 + (i & 63)];
  float mean2 = block_sum(s2, red, tid) * (1.f / 1600.f);
  float sq2 = 0.f;
  for (int i = tid; i < 1600; i += 256) {
    float d = z6l[(i >> 6) * 68 + (i & 63)] - mean2;
    sq2 += d * d;
  }
  float inv2 = rsqrtf(block_sum(sq2, red, tid) * (1.f / 1600.f) + 1e-5f);
  for (int i = tid; i < 1600; i += 256) {
    int o = (i >> 6) * 68 + (i & 63);
    zf[base + i] = gelu_f(yts[(i >> 6) * 66 + (i & 63)] + (z6l[o] - mean2) * inv2 * g2[i] + b2[i]);
  }
}

// conv weight transpose: wT[(dt*64+c)*64+c'] = w[(c'*64+c)*7+dt]
__global__ void convw_transpose(const float* __restrict__ w, float* __restrict__ wT) {
  int idx = blockIdx.x * 256 + threadIdx.x;
  if (idx < 64 * 64 * 7) {
    int dt = idx % 7, c = (idx / 7) % 64, cp = idx / 448;
    wT[(dt * 64 + c) * 64 + cp] = w[idx];
  }
}

// ---------------------------------------------------------------------------
// Conv 7x1 along T + bias, block per (n,t); per-block BN partial sums.
// ---------------------------------------------------------------------------
__launch_bounds__(256, 2)
__global__ void conv_kernel(const float* __restrict__ zf, const float* __restrict__ wT,
                            const float* __restrict__ cb, float* __restrict__ z1,
                            float* __restrict__ part) {
  __shared__ float lz[7 * 1600];
  __shared__ float lw[64 * 68];
  __shared__ float red[256], red2[256];
  const int b = blockIdx.x;
  const int n = b / 64, t = b % 64;
  const int tid = threadIdx.x;
  for (int idx = tid; idx < 7 * 1600; idx += 256) {
    int dt = idx / 1600, r = idx - dt * 1600;
    int tt = t + dt - 3;
    lz[idx] = (tt >= 0 && tt < 64) ? zf[(size_t)(n * 64 + tt) * 1600 + r] : 0.f;
  }
  const int cp = tid & 63, vg = tid >> 6;
  float acc[7];
#pragma unroll
  for (int vi = 0; vi < 7; ++vi) acc[vi] = cb[cp];
  const int nvi = (vg == 0) ? 7 : 6;
  for (int dt = 0; dt < 7; ++dt) {
    __syncthreads();
    for (int idx = tid; idx < 4096; idx += 256) {
      int c = idx >> 6, cc = idx & 63;
      lw[cc * 68 + c] = wT[(dt * 64 + c) * 64 + cc];
    }
    __syncthreads();
#pragma unroll
    for (int c4 = 0; c4 < 16; ++c4) {
      float4 wv = *(const float4*)&lw[cp * 68 + c4 * 4];
#pragma unroll
      for (int vi = 0; vi < 7; ++vi) {
        int v = vg + 4 * vi;
        if (v < 25) {
          float4 zv = *(const float4*)&lz[dt * 1600 + v * 64 + c4 * 4];
          acc[vi] += wv.x * zv.x + wv.y * zv.y + wv.z * zv.z + wv.w * zv.w;
        }
      }
    }
  }
  float lsum = 0.f, lsq = 0.f;
  for (int vi = 0; vi < nvi; ++vi) {
    int v = vg + 4 * vi;
    z1[(size_t)((n * 64 + t) * 25 + v) * 64 + cp] = acc[vi];
    lsum += acc[vi];
    lsq += acc[vi] * acc[vi];
  }
  red[tid] = lsum;
  red2[tid] = lsq;
  __syncthreads();
  if (tid < 64) {
    float s = red[tid] + red[tid + 64] + red[tid + 128] + red[tid + 192];
    float q = red2[tid] + red2[tid + 64] + red2[tid + 128] + red2[tid + 192];
    part[(size_t)b * 128 + tid] = s;
    part[(size_t)b * 128 + 64 + tid] = q;
  }
}

__global__ void bn_final(const float* __restrict__ part, const float* __restrict__ g,
                         const float* __restrict__ bb, float* __restrict__ sc) {
  __shared__ float red[256], red2[256];
  const int c = blockIdx.x;
  const int tid = threadIdx.x;
  float s = 0.f, q = 0.f;
  for (int i = tid; i < 8192; i += 256) {
    s += part[(size_t)i * 128 + c];
    q += part[(size_t)i * 128 + 64 + c];
  }
  red[tid] = s;
  red2[tid] = q;
  __syncthreads();
#pragma unroll
  for (int o = 128; o > 0; o >>= 1) {
    if (tid < o) { red[tid] += red[tid + o]; red2[tid] += red2[tid + o]; }
    __syncthreads();
  }
  if (tid == 0) {
    const float M = 204800.f;
    float mean = red[0] / M;
    float var = red2[0] / M - mean * mean;
    float scale = g[c] * rsqrtf(var + 1e-5f);
    sc[c] = scale;
    sc[64 + c] = bb[c] - mean * scale;
  }
}

__global__ void final_kernel(const float* __restrict__ zf, const float* __restrict__ z1,
                             const float* __restrict__ sc, float* __restrict__ out) {
  const int b = blockIdx.x;
  const int n = b / 64, t = b % 64;
  const int tid = threadIdx.x;
  const size_t base = (size_t)(n * 64 + t) * 1600;
  for (int i = tid; i < 1600; i += 256) {
    int v = i >> 6, c = i & 63;
    float val = zf[base + i] + z1[base + i] * sc[c] + sc[64 + c];
    out[(size_t)((n * 25 + v) * 64 + t) * 64 + c] = gelu_f(val);
  }
}

}  // namespace

extern "C" void kernel_launch(void* const* d_in, const int* in_sizes, int n_in,
                              void* d_out, int out_size, void* d_ws, size_t ws_size,
                              hipStream_t stream) {
  (void)in_sizes; (void)n_in; (void)out_size; (void)ws_size;
  const float* x          = (const float*)d_in[0];
  const float* w_in_s     = (const float*)d_in[1];
  const float* b_in_s     = (const float*)d_in[2];
  const float* alphas     = (const float*)d_in[3];
  const float* att0s      = (const float*)d_in[4];
  const float* w_out_s    = (const float*)d_in[5];
  const float* b_out_s    = (const float*)d_in[6];
  const float* ln_out_s_g = (const float*)d_in[7];
  const float* ln_out_s_b = (const float*)d_in[8];
  const float* w_ff_s     = (const float*)d_in[9];
  const float* b_ff_s     = (const float*)d_in[10];
  const float* ln_ff_s_g  = (const float*)d_in[11];
  const float* ln_ff_s_b  = (const float*)d_in[12];
  const float* w_in_t     = (const float*)d_in[13];
  const float* b_in_t     = (const float*)d_in[14];
  const float* alphat_f   = (const float*)d_in[15];
  const float* alphat_b   = (const float*)d_in[16];
  const float* w_out_t    = (const float*)d_in[17];
  const float* b_out_t    = (const float*)d_in[18];
  const float* ln_out_t_g = (const float*)d_in[19];
  const float* ln_out_t_b = (const float*)d_in[20];
  const float* w_ff_t     = (const float*)d_in[21];
  const float* b_ff_t     = (const float*)d_in[22];
  const float* ln_ff_t_g  = (const float*)d_in[23];
  const float* ln_ff_t_b  = (const float*)d_in[24];
  const float* conv_w     = (const float*)d_in[25];
  const float* conv_b     = (const float*)d_in[26];
  const float* bn_g       = (const float*)d_in[27];
  const float* bn_b       = (const float*)d_in[28];
  float* out = (float*)d_out;
  float* ws = (float*)d_ws;

  // Workspace (floats): total 54,525,952 = 218.1 MB (< 262 MB proven).
  //  [0 .. 2.10M)  att4 (steps 6-7); then part/wT/bnsc (steps 9-11)
  //  [2.10M..28.3M) R: qk(1-2) / y2(3-4) / qkt(5-6) / z1b(9-11)
  //  [28.3M..41.4M) yt (4-8)
  //  [41.4M..54.5M) zf (8-11)
  // d_out doubles as att_s (2-3) and z2 (7-8) scratch.
  float* att4 = ws;
  float* part = ws;                    // 8192*128, live 9-10 (att4 dead)
  float* wT   = ws + 1048576;          // 28672
  float* bnsc = ws + 1080000;          // 128
  float* qk   = ws + 2097152;          // 19,660,800
  float* y2   = ws + 2097152;          // 13,107,200
  float* qkt  = ws + 2097152;          // 26,214,400
  float* z1b  = ws + 2097152;          // 13,107,200
  float* yt   = ws + 28311552;         // 13,107,200
  float* zf   = ws + 41418752;         // 13,107,200
  float* att_s = out;                  // 240,000 (dead before step 7)
  float* z2    = out;                  // full out (dead before final)

  dim3 blk(256);
  // ---- spatial ----
  gemm_k64<96><<<3200, blk, 0, stream>>>(x, w_in_s, b_in_s, qk);
  att_s_kernel<<<128 * 7, blk, 0, stream>>>(qk, alphas, att0s, att_s);
  mix_gemm_s<<<8192, blk, 0, stream>>>(x, att_s, w_out_s, b_out_s, y2);
  lnln_s_kernel<<<3200, blk, 0, stream>>>(y2, x, w_ff_s, b_ff_s, ln_out_s_g, ln_out_s_b,
                                          ln_ff_s_g, ln_ff_s_b, yt);
  // ---- temporal ----
  gemm_k64<128><<<3200, blk, 0, stream>>>(yt, w_in_t, b_in_t, qkt);
  att_t_kernel<<<128 * 8, blk, 0, stream>>>(qkt, alphat_f, alphat_b, att4);
  mix_gemm_t<<<6400, blk, 0, stream>>>(yt, att4, w_out_t, b_out_t, z2);
  lnln_t_kernel<<<8192, blk, 0, stream>>>(z2, yt, w_ff_t, b_ff_t, ln_out_t_g, ln_out_t_b,
                                          ln_ff_t_g, ln_ff_t_b, zf);
  // ---- conv + BN + output ----
  convw_transpose<<<112, blk, 0, stream>>>(conv_w, wT);
  conv_kernel<<<8192, blk, 0, stream>>>(zf, wT, conv_b, z1b, part);
  bn_final<<<64, blk, 0, stream>>>(part, bn_g, bn_b, bnsc);
  final_kernel<<<8192, blk, 0, stream>>>(zf, z1b, bnsc, out);
}

// Round 5
// 2595.800 us; speedup vs baseline: 1.8824x; 1.2319x over previous
//
#include <hip/hip_runtime.h>
#include <math.h>

namespace {

constexpr int V_ = 25, T_ = 64, C_ = 64;

__device__ __forceinline__ float gelu_f(float x) {
  return 0.5f * x * (1.0f + erff(x * 0.7071067811865475f));
}

__device__ __forceinline__ float block_sum(float v, float* red, int tid) {
  red[tid] = v; __syncthreads();
#pragma unroll
  for (int o = 128; o > 0; o >>= 1) {
    if (tid < o) red[tid] += red[tid + o];
    __syncthreads();
  }
  float r = red[0]; __syncthreads();
  return r;
}

// ---------------------------------------------------------------------------
// K=64 GEMM: C[204800 x NC] = A[204800 x 64] @ B[64 x NC] + bias.
// ---------------------------------------------------------------------------
template <int NC>
__launch_bounds__(256, 2)
__global__ void gemm_k64(const float* __restrict__ A, const float* __restrict__ B,
                         const float* __restrict__ bias, float* __restrict__ C) {
  __shared__ float Al[64 * 68];
  __shared__ float Bl[64 * (NC + 4)];
  const int tid = threadIdx.x;
  const int row0 = blockIdx.x * 64;
  for (int i = tid; i < 4096; i += 256)
    Al[(i >> 6) * 68 + (i & 63)] = A[(size_t)(row0 + (i >> 6)) * 64 + (i & 63)];
  for (int i = tid; i < 64 * NC; i += 256) {
    int k = i / NC, c = i - k * NC;
    Bl[k * (NC + 4) + c] = B[i];
  }
  __syncthreads();
  const int ri = tid >> 5, cg = tid & 31;
  if (cg * 4 < NC) {
    float4 acc[8];
    float4 bf = *(const float4*)&bias[cg * 4];
#pragma unroll
    for (int i = 0; i < 8; ++i) acc[i] = bf;
    for (int k0 = 0; k0 < 64; k0 += 4) {
      float4 bv0 = *(const float4*)&Bl[(k0 + 0) * (NC + 4) + cg * 4];
      float4 bv1 = *(const float4*)&Bl[(k0 + 1) * (NC + 4) + cg * 4];
      float4 bv2 = *(const float4*)&Bl[(k0 + 2) * (NC + 4) + cg * 4];
      float4 bv3 = *(const float4*)&Bl[(k0 + 3) * (NC + 4) + cg * 4];
#pragma unroll
      for (int i = 0; i < 8; ++i) {
        float4 av = *(const float4*)&Al[(ri * 8 + i) * 68 + k0];
        acc[i].x += av.x * bv0.x + av.y * bv1.x + av.z * bv2.x + av.w * bv3.x;
        acc[i].y += av.x * bv0.y + av.y * bv1.y + av.z * bv2.y + av.w * bv3.y;
        acc[i].z += av.x * bv0.z + av.y * bv1.z + av.z * bv2.z + av.w * bv3.z;
        acc[i].w += av.x * bv0.w + av.y * bv1.w + av.z * bv2.w + av.w * bv3.w;
      }
    }
#pragma unroll
    for (int i = 0; i < 8; ++i)
      *(float4*)&C[(size_t)(row0 + ri * 8 + i) * NC + cg * 4] = acc[i];
  }
}

// ---------------------------------------------------------------------------
// Spatial attention scores. Block = (n, u-quad).
// ---------------------------------------------------------------------------
__global__ void att_s_kernel(const float* __restrict__ qk, const float* __restrict__ alphas,
                             const float* __restrict__ att0, float* __restrict__ att) {
  __shared__ float qs[4 * 3072];
  __shared__ float ks[3072];
  const int b = blockIdx.x, tid = threadIdx.x;
  const int n = b / 7, ug = b % 7;
  const int u0 = ug * 4;
  const int nu = (25 - u0 < 4) ? (25 - u0) : 4;
  for (int i = tid; i < nu * 3072; i += 256) {
    int ul = i / 3072, r = i - ul * 3072;
    int s = r >> 10, idx = r & 1023, t = idx >> 4, c = idx & 15;
    qs[i] = qk[(size_t)(n * 25 + u0 + ul) * 6144 + t * 96 + c * 6 + s];
  }
  const int ui = tid >> 6, l = tid & 63;
  const int u = u0 + ui;
  const float a0 = alphas[0], a1 = alphas[1], a2 = alphas[2];
  for (int v = 0; v < 25; ++v) {
    __syncthreads();
    for (int i = tid; i < 3072; i += 256) {
      int s = i >> 10, idx = i & 1023, t = idx >> 4, c = idx & 15;
      ks[i] = qk[(size_t)(n * 25 + v) * 6144 + t * 96 + c * 6 + 3 + s];
    }
    __syncthreads();
    if (u < 25) {
      float s0 = 0.f, s1 = 0.f, s2 = 0.f;
      for (int idx = l; idx < 1024; idx += 64) {
        s0 += qs[ui * 3072 + idx] * ks[idx];
        s1 += qs[ui * 3072 + 1024 + idx] * ks[1024 + idx];
        s2 += qs[ui * 3072 + 2048 + idx] * ks[2048 + idx];
      }
#pragma unroll
      for (int o = 32; o > 0; o >>= 1) {
        s0 += __shfl_down(s0, o);
        s1 += __shfl_down(s1, o);
        s2 += __shfl_down(s2, o);
      }
      if (l == 0) {
        float* dst = &att[(size_t)((n * 25 + u) * 25 + v) * 3];
        const float* ap = &att0[(u * 25 + v) * 3];
        dst[0] = tanhf(s0 * (1.f / 1024.f)) * a0 + ap[0];
        dst[1] = tanhf(s1 * (1.f / 1024.f)) * a1 + ap[1];
        dst[2] = tanhf(s2 * (1.f / 1024.f)) * a2 + ap[2];
      }
    }
  }
}

// ---------------------------------------------------------------------------
// Fused spatial mix + out-projection. Block (n,t).
// ---------------------------------------------------------------------------
__launch_bounds__(256, 2)
__global__ void mix_gemm_s(const float* __restrict__ x, const float* __restrict__ att,
                           const float* __restrict__ w, const float* __restrict__ bias,
                           float* __restrict__ y2) {
  __shared__ float la[1875];
  __shared__ float xs[1600];
  __shared__ float y1l[25 * 194];
  __shared__ float wl[192 * 36];
  const int b = blockIdx.x, tid = threadIdx.x;
  const int n = b >> 6, t = b & 63;
  for (int i = tid; i < 1875; i += 256) la[i] = att[(size_t)n * 1875 + i];
  for (int i = tid; i < 1600; i += 256) {
    int u = i >> 6, c = i & 63;
    xs[i] = x[(size_t)((n * 25 + u) * 64 + t) * 64 + c];
  }
  __syncthreads();
  for (int slot = tid; slot < 400; slot += 256) {
    int v = slot >> 4, cg = slot & 15;
    float4 s0 = {0, 0, 0, 0}, s1 = {0, 0, 0, 0}, s2 = {0, 0, 0, 0};
    for (int u = 0; u < 25; ++u) {
      float4 xv = *(const float4*)&xs[u * 64 + cg * 4];
      const float* lp = &la[(u * 25 + v) * 3];
      float w0 = lp[0], w1 = lp[1], w2 = lp[2];
      s0.x += xv.x * w0; s0.y += xv.y * w0; s0.z += xv.z * w0; s0.w += xv.w * w0;
      s1.x += xv.x * w1; s1.y += xv.y * w1; s1.z += xv.z * w1; s1.w += xv.w * w1;
      s2.x += xv.x * w2; s2.y += xv.y * w2; s2.z += xv.z * w2; s2.w += xv.w * w2;
    }
    float* yp = &y1l[v * 194 + cg * 12];
    yp[0] = s0.x; yp[1] = s1.x; yp[2] = s2.x;
    yp[3] = s0.y; yp[4] = s1.y; yp[5] = s2.y;
    yp[6] = s0.z; yp[7] = s1.z; yp[8] = s2.z;
    yp[9] = s0.w; yp[10] = s1.w; yp[11] = s2.w;
  }
  for (int h = 0; h < 2; ++h) {
    __syncthreads();
    for (int i = tid; i < 192 * 32; i += 256) {
      int k = i >> 5, cc = i & 31;
      wl[k * 36 + cc] = w[k * 64 + h * 32 + cc];
    }
    __syncthreads();
    if (tid < 200) {
      int v = tid >> 3, cp = tid & 7;
      float4 acc = *(const float4*)&bias[h * 32 + cp * 4];
      for (int k = 0; k < 192; ++k) {
        float yv = y1l[v * 194 + k];
        float4 wv = *(const float4*)&wl[k * 36 + cp * 4];
        acc.x += yv * wv.x; acc.y += yv * wv.y; acc.z += yv * wv.z; acc.w += yv * wv.w;
      }
      *(float4*)&y2[(size_t)((n * 25 + v) * 64 + t) * 64 + h * 32 + cp * 4] = acc;
    }
  }
}

// ---------------------------------------------------------------------------
// Fused LN -> gelu(x+.) -> @w_ff -> LN -> gelu(x+.) (spatial). Block (n,v).
// ---------------------------------------------------------------------------
__global__ void lnln_s_kernel(const float* __restrict__ y2, const float* __restrict__ x,
                              const float* __restrict__ wff, const float* __restrict__ bff,
                              const float* __restrict__ g1, const float* __restrict__ b1,
                              const float* __restrict__ g2, const float* __restrict__ b2,
                              float* __restrict__ yt) {
  __shared__ float ya[64 * 66];
  __shared__ float wl[64 * 68];
  __shared__ float y6l[64 * 68];
  __shared__ float red[256];
  const int g = blockIdx.x, tid = threadIdx.x;
  const int n = g / 25, v = g % 25;
  const size_t base = (size_t)g * 4096;
  float s = 0.f;
  for (int i = tid; i < 4096; i += 256) {
    float val = y2[base + i];
    ya[(i >> 6) * 66 + (i & 63)] = val;
    s += val;
  }
  for (int i = tid; i < 4096; i += 256) wl[(i >> 6) * 68 + (i & 63)] = wff[i];
  float mean = block_sum(s, red, tid) * (1.f / 4096.f);
  float sq = 0.f;
  for (int i = tid; i < 4096; i += 256) {
    float d = ya[(i >> 6) * 66 + (i & 63)] - mean;
    sq += d * d;
  }
  float inv = rsqrtf(block_sum(sq, red, tid) * (1.f / 4096.f) + 1e-5f);
  for (int i = tid; i < 4096; i += 256) {
    int o = (i >> 6) * 66 + (i & 63);
    ya[o] = gelu_f(x[base + i] + (ya[o] - mean) * inv * g1[i] + b1[i]);
  }
  __syncthreads();
  const int ri = tid >> 4, ci = tid & 15;
  {
    float4 bf = *(const float4*)&bff[ci * 4];
    float4 acc[4];
#pragma unroll
    for (int i = 0; i < 4; ++i) acc[i] = bf;
    for (int k = 0; k < 64; ++k) {
      float4 wv = *(const float4*)&wl[k * 68 + ci * 4];
#pragma unroll
      for (int i = 0; i < 4; ++i) {
        float av = ya[(ri + 16 * i) * 66 + k];
        acc[i].x += av * wv.x; acc[i].y += av * wv.y;
        acc[i].z += av * wv.z; acc[i].w += av * wv.w;
      }
    }
#pragma unroll
    for (int i = 0; i < 4; ++i)
      *(float4*)&y6l[(ri + 16 * i) * 68 + ci * 4] = acc[i];
  }
  __syncthreads();
  float s2 = 0.f;
  for (int i = tid; i < 4096; i += 256) s2 += y6l[(i >> 6) * 68 + (i & 63)];
  float mean2 = block_sum(s2, red, tid) * (1.f / 4096.f);
  float sq2 = 0.f;
  for (int i = tid; i < 4096; i += 256) {
    float d = y6l[(i >> 6) * 68 + (i & 63)] - mean2;
    sq2 += d * d;
  }
  float inv2 = rsqrtf(block_sum(sq2, red, tid) * (1.f / 4096.f) + 1e-5f);
  for (int i = tid; i < 4096; i += 256) {
    int t = i >> 6, c = i & 63;
    yt[(size_t)((n * 64 + t) * 25 + v) * 64 + c] =
        gelu_f(x[base + i] + (y6l[t * 68 + c] - mean2) * inv2 * g2[i] + b2[i]);
  }
}

// ---------------------------------------------------------------------------
// Temporal attention scores. Block = (n, t-oct).
// ---------------------------------------------------------------------------
__global__ void att_t_kernel(const float* __restrict__ qkt, const float* __restrict__ af_al,
                             const float* __restrict__ ab_al, float* __restrict__ att4) {
  __shared__ float qs[8 * 1600];
  __shared__ float ks[1600];
  const int b = blockIdx.x, tid = threadIdx.x;
  const int n = b >> 3, to = b & 7;
  for (int i = tid; i < 8 * 1600; i += 256) {
    int tt = i / 1600, r = i - tt * 1600;
    int pair = r >> 2, j = r & 3, v = pair >> 4, c = pair & 15;
    qs[i] = qkt[(size_t)((n * 64 + to * 8 + tt) * 25 + v) * 128 + c * 8 + j];
  }
  const int tt = tid >> 5, l = tid & 31;
  const int t = to * 8 + tt;
  const float af0 = af_al[0], af1 = af_al[1], ab0 = ab_al[0], ab1 = ab_al[1];
  for (int q = 0; q < 64; ++q) {
    __syncthreads();
    for (int i = tid; i < 1600; i += 256) {
      int pair = i >> 2, j = i & 3, v = pair >> 4, c = pair & 15;
      ks[i] = qkt[(size_t)((n * 64 + q) * 25 + v) * 128 + c * 8 + 4 + j];
    }
    __syncthreads();
    float f0 = 0.f, f1 = 0.f, b0 = 0.f, b1 = 0.f;
    for (int idx = l; idx < 400; idx += 32) {
      float4 q4 = *(const float4*)&qs[tt * 1600 + idx * 4];
      float4 k4 = *(const float4*)&ks[idx * 4];
      f0 += q4.x * k4.x; f1 += q4.y * k4.y;
      b0 += q4.z * k4.z; b1 += q4.w * k4.w;
    }
#pragma unroll
    for (int o = 16; o > 0; o >>= 1) {
      f0 += __shfl_down(f0, o, 32); f1 += __shfl_down(f1, o, 32);
      b0 += __shfl_down(b0, o, 32); b1 += __shfl_down(b1, o, 32);
    }
    if (l == 0) {
      float mf = (q <= t) ? 1.f : 0.f;
      float mb = (q >= t) ? 1.f : 0.f;
      size_t o4 = ((size_t)(n * 4 + 0) * 64 + t) * 64 + q;
      att4[o4]           = tanhf(f0 * (1.f / 400.f)) * af0 * mf;
      att4[o4 + 4096]    = tanhf(f1 * (1.f / 400.f)) * af1 * mf;
      att4[o4 + 2 * 4096] = tanhf(b0 * (1.f / 400.f)) * ab0 * mb;
      att4[o4 + 3 * 4096] = tanhf(b1 * (1.f / 400.f)) * ab1 * mb;
    }
  }
}

// ---------------------------------------------------------------------------
// Fused temporal mix + out-projection. Block (n, v, q-half).
// ---------------------------------------------------------------------------
__launch_bounds__(256, 2)
__global__ void mix_gemm_t(const float* __restrict__ yt, const float* __restrict__ att4,
                           const float* __restrict__ w, const float* __restrict__ bias,
                           float* __restrict__ z2) {
  __shared__ float smem[12288];
  float* as4 = smem;
  float* ys = smem + 8192;
  float* zvl = smem;
  const int b = blockIdx.x, tid = threadIdx.x;
  const int n = b / 50, r = b % 50;
  const int v = r >> 1, qh = r & 1;
  const int q0b = qh * 32;
  for (int i = tid; i < 8192; i += 256) {
    int sdi = i >> 11, t = (i >> 5) & 63, qq = i & 31;
    as4[i] = att4[((size_t)(n * 4 + sdi) * 64 + t) * 64 + q0b + qq];
  }
  for (int i = tid; i < 4096; i += 256) {
    int t = i >> 6, c = i & 63;
    ys[i] = yt[(size_t)((n * 64 + t) * 25 + v) * 64 + c];
  }
  __syncthreads();
  const int qg = tid >> 4, cg = tid & 15;
  const int q0 = qg * 2, c0 = cg * 4;
  float4 a00 = {0,0,0,0}, a01 = {0,0,0,0}, a10 = {0,0,0,0}, a11 = {0,0,0,0};
  float4 a20 = {0,0,0,0}, a21 = {0,0,0,0}, a30 = {0,0,0,0}, a31 = {0,0,0,0};
  for (int t = 0; t < 64; ++t) {
    float4 bv = *(const float4*)&ys[t * 64 + c0];
    float2 av0 = *(const float2*)&as4[(0 * 64 + t) * 32 + q0];
    float2 av1 = *(const float2*)&as4[(1 * 64 + t) * 32 + q0];
    float2 av2 = *(const float2*)&as4[(2 * 64 + t) * 32 + q0];
    float2 av3 = *(const float2*)&as4[(3 * 64 + t) * 32 + q0];
#define FMA4S(A, S) A.x += bv.x * (S); A.y += bv.y * (S); A.z += bv.z * (S); A.w += bv.w * (S)
    FMA4S(a00, av0.x); FMA4S(a01, av0.y);
    FMA4S(a10, av1.x); FMA4S(a11, av1.y);
    FMA4S(a20, av2.x); FMA4S(a21, av2.y);
    FMA4S(a30, av3.x); FMA4S(a31, av3.y);
#undef FMA4S
  }
  __syncthreads();
#define STORE_ZV(A, SDI, QI)                                                     \
  { int cb = ((SDI) >= 2 ? 128 : 0) + ((SDI) & 1);                               \
    float* zp = &zvl[(q0 + (QI)) * 258 + cb];                                    \
    zp[(c0 + 0) * 2] = A.x; zp[(c0 + 1) * 2] = A.y;                              \
    zp[(c0 + 2) * 2] = A.z; zp[(c0 + 3) * 2] = A.w; }
  STORE_ZV(a00, 0, 0); STORE_ZV(a01, 0, 1);
  STORE_ZV(a10, 1, 0); STORE_ZV(a11, 1, 1);
  STORE_ZV(a20, 2, 0); STORE_ZV(a21, 2, 1);
  STORE_ZV(a30, 3, 0); STORE_ZV(a31, 3, 1);
#undef STORE_ZV
  __syncthreads();
  const int qg2 = tid >> 6, cp = tid & 63;
  float acc2[8] = {0, 0, 0, 0, 0, 0, 0, 0};
  for (int col = 0; col < 256; ++col) {
    float wv = w[col * 64 + cp];
#pragma unroll
    for (int qi = 0; qi < 8; ++qi) acc2[qi] += zvl[(qg2 * 8 + qi) * 258 + col] * wv;
  }
  float bb = bias[cp];
#pragma unroll
  for (int qi = 0; qi < 8; ++qi)
    z2[(size_t)((n * 64 + q0b + qg2 * 8 + qi) * 25 + v) * 64 + cp] = acc2[qi] + bb;
}

// ---------------------------------------------------------------------------
// Fused LN -> gelu(y+.) -> @w_ff_t -> LN -> gelu(y+.) (temporal). Block (n,q).
// ---------------------------------------------------------------------------
__global__ void lnln_t_kernel(const float* __restrict__ z2, const float* __restrict__ ytr,
                              const float* __restrict__ wff, const float* __restrict__ bff,
                              const float* __restrict__ g1, const float* __restrict__ b1,
                              const float* __restrict__ g2, const float* __restrict__ b2,
                              float* __restrict__ zf) {
  __shared__ float za[25 * 66];
  __shared__ float yts[25 * 66];
  __shared__ float wl[64 * 68];
  __shared__ float z6l[25 * 68];
  __shared__ float red[256];
  const int g = blockIdx.x, tid = threadIdx.x;
  const size_t base = (size_t)g * 1600;
  float s = 0.f;
  for (int i = tid; i < 1600; i += 256) {
    float val = z2[base + i];
    za[(i >> 6) * 66 + (i & 63)] = val;
    yts[(i >> 6) * 66 + (i & 63)] = ytr[base + i];
    s += val;
  }
  for (int i = tid; i < 4096; i += 256) wl[(i >> 6) * 68 + (i & 63)] = wff[i];
  float mean = block_sum(s, red, tid) * (1.f / 1600.f);
  float sq = 0.f;
  for (int i = tid; i < 1600; i += 256) {
    float d = za[(i >> 6) * 66 + (i & 63)] - mean;
    sq += d * d;
  }
  float inv = rsqrtf(block_sum(sq, red, tid) * (1.f / 1600.f) + 1e-5f);
  for (int i = tid; i < 1600; i += 256) {
    int o = (i >> 6) * 66 + (i & 63);
    za[o] = gelu_f(yts[o] + (za[o] - mean) * inv * g1[i] + b1[i]);
  }
  __syncthreads();
  for (int slot = tid; slot < 400; slot += 256) {
    int v = slot >> 4, cq = slot & 15;
    float4 acc = *(const float4*)&bff[cq * 4];
    for (int k = 0; k < 64; ++k) {
      float av = za[v * 66 + k];
      float4 wv = *(const float4*)&wl[k * 68 + cq * 4];
      acc.x += av * wv.x; acc.y += av * wv.y; acc.z += av * wv.z; acc.w += av * wv.w;
    }
    *(float4*)&z6l[v * 68 + cq * 4] = acc;
  }
  __syncthreads();
  float s2 = 0.f;
  for (int i = tid; i < 1600; i += 256) s2 += z6l[(i >> 6) * 68 + (i & 63)];
  float mean2 = block_sum(s2, red, tid) * (1.f / 1600.f);
  float sq2 = 0.f;
  for (int i = tid; i < 1600; i += 256) {
    float d = z6l[(i >> 6) * 68 + (i & 63)] - mean2;
    sq2 += d * d;
  }
  float inv2 = rsqrtf(block_sum(sq2, red, tid) * (1.f / 1600.f) + 1e-5f);
  for (int i = tid; i < 1600; i += 256) {
    int o = (i >> 6) * 68 + (i & 63);
    zf[base + i] = gelu_f(yts[(i >> 6) * 66 + (i & 63)] + (z6l[o] - mean2) * inv2 * g2[i] + b2[i]);
  }
}

// conv weight transpose: wT[(dt*64+c)*64+c'] = w[(c'*64+c)*7+dt]
__global__ void convw_transpose(const float* __restrict__ w, float* __restrict__ wT) {
  int idx = blockIdx.x * 256 + threadIdx.x;
  if (idx < 64 * 64 * 7) {
    int dt = idx % 7, c = (idx / 7) % 64, cp = idx / 448;
    wT[(dt * 64 + c) * 64 + cp] = w[idx];
  }
}

// ---------------------------------------------------------------------------
// Conv as K=448 GEMM with 7 t-shifted A-tiles. Block = 128 rows x 64 cols.
// Rows are flat (n,t,v); A-chunk dt = zf rows shifted by (dt-3)*25, zero-
// padded when t+dt-3 leaves [0,64). Thread = 8 rows (ri+16*i, bank-spread)
// x float4 cols. Inner: 12 b128 reads per 128 FMA. BN partials per block.
// ---------------------------------------------------------------------------
__launch_bounds__(256, 2)
__global__ void conv_gemm(const float* __restrict__ zf, const float* __restrict__ wT,
                          const float* __restrict__ cb, float* __restrict__ z1,
                          float* __restrict__ part) {
  __shared__ float Al[128 * 68];   // 34.8 KB
  __shared__ float Bl[64 * 68];    // 17.4 KB
  const int tid = threadIdx.x;
  const int r0 = blockIdx.x * 128;
  const int ri = tid >> 4;         // 0..15
  const int cg = tid & 15;         // 0..15
  float4 acc[8];
  float4 bf = *(const float4*)&cb[cg * 4];
#pragma unroll
  for (int i = 0; i < 8; ++i) acc[i] = bf;
  for (int dt = 0; dt < 7; ++dt) {
    __syncthreads();
    for (int i = tid; i < 8192; i += 256) {
      int rl = i >> 6, c = i & 63;
      int grow = r0 + rl;
      int t = (grow % 1600) / 25;
      int tt = t + dt - 3;
      float val = 0.f;
      if (tt >= 0 && tt < 64)
        val = zf[(size_t)(grow + (dt - 3) * 25) * 64 + c];
      Al[rl * 68 + c] = val;
    }
    for (int i = tid; i < 4096; i += 256)
      Bl[(i >> 6) * 68 + (i & 63)] = wT[dt * 4096 + i];
    __syncthreads();
    for (int k0 = 0; k0 < 64; k0 += 4) {
      float4 bv0 = *(const float4*)&Bl[(k0 + 0) * 68 + cg * 4];
      float4 bv1 = *(const float4*)&Bl[(k0 + 1) * 68 + cg * 4];
      float4 bv2 = *(const float4*)&Bl[(k0 + 2) * 68 + cg * 4];
      float4 bv3 = *(const float4*)&Bl[(k0 + 3) * 68 + cg * 4];
#pragma unroll
      for (int i = 0; i < 8; ++i) {
        float4 av = *(const float4*)&Al[(ri + 16 * i) * 68 + k0];
        acc[i].x += av.x * bv0.x + av.y * bv1.x + av.z * bv2.x + av.w * bv3.x;
        acc[i].y += av.x * bv0.y + av.y * bv1.y + av.z * bv2.y + av.w * bv3.y;
        acc[i].z += av.x * bv0.z + av.y * bv1.z + av.z * bv2.z + av.w * bv3.z;
        acc[i].w += av.x * bv0.w + av.y * bv1.w + av.z * bv2.w + av.w * bv3.w;
      }
    }
  }
  float4 psum = {0, 0, 0, 0}, psq = {0, 0, 0, 0};
#pragma unroll
  for (int i = 0; i < 8; ++i) {
    *(float4*)&z1[(size_t)(r0 + ri + 16 * i) * 64 + cg * 4] = acc[i];
    psum.x += acc[i].x; psum.y += acc[i].y; psum.z += acc[i].z; psum.w += acc[i].w;
    psq.x += acc[i].x * acc[i].x; psq.y += acc[i].y * acc[i].y;
    psq.z += acc[i].z * acc[i].z; psq.w += acc[i].w * acc[i].w;
  }
  __syncthreads();
  *(float4*)&Al[ri * 68 + cg * 4] = psum;
  *(float4*)&Bl[ri * 68 + cg * 4] = psq;
  __syncthreads();
  if (tid < 64) {
    float s = 0.f, q = 0.f;
    for (int r = 0; r < 16; ++r) {
      s += Al[r * 68 + tid];
      q += Bl[r * 68 + tid];
    }
    part[(size_t)blockIdx.x * 128 + tid] = s;
    part[(size_t)blockIdx.x * 128 + 64 + tid] = q;
  }
}

// Per-channel BN stats -> scale/shift. One block per channel.
__global__ void bn_final(const float* __restrict__ part, const float* __restrict__ g,
                         const float* __restrict__ bb, float* __restrict__ sc) {
  __shared__ float red[256], red2[256];
  const int c = blockIdx.x;
  const int tid = threadIdx.x;
  float s = 0.f, q = 0.f;
  for (int i = tid; i < 1600; i += 256) {
    s += part[(size_t)i * 128 + c];
    q += part[(size_t)i * 128 + 64 + c];
  }
  red[tid] = s;
  red2[tid] = q;
  __syncthreads();
#pragma unroll
  for (int o = 128; o > 0; o >>= 1) {
    if (tid < o) { red[tid] += red[tid + o]; red2[tid] += red2[tid + o]; }
    __syncthreads();
  }
  if (tid == 0) {
    const float M = 204800.f;
    float mean = red[0] / M;
    float var = red2[0] / M - mean * mean;
    float scale = g[c] * rsqrtf(var + 1e-5f);
    sc[c] = scale;
    sc[64 + c] = bb[c] - mean * scale;
  }
}

__global__ void final_kernel(const float* __restrict__ zf, const float* __restrict__ z1,
                             const float* __restrict__ sc, float* __restrict__ out) {
  const int b = blockIdx.x;
  const int n = b / 64, t = b % 64;
  const int tid = threadIdx.x;
  const size_t base = (size_t)(n * 64 + t) * 1600;
  for (int i = tid; i < 1600; i += 256) {
    int v = i >> 6, c = i & 63;
    float val = zf[base + i] + z1[base + i] * sc[c] + sc[64 + c];
    out[(size_t)((n * 25 + v) * 64 + t) * 64 + c] = gelu_f(val);
  }
}

}  // namespace

extern "C" void kernel_launch(void* const* d_in, const int* in_sizes, int n_in,
                              void* d_out, int out_size, void* d_ws, size_t ws_size,
                              hipStream_t stream) {
  (void)in_sizes; (void)n_in; (void)out_size; (void)ws_size;
  const float* x          = (const float*)d_in[0];
  const float* w_in_s     = (const float*)d_in[1];
  const float* b_in_s     = (const float*)d_in[2];
  const float* alphas     = (const float*)d_in[3];
  const float* att0s      = (const float*)d_in[4];
  const float* w_out_s    = (const float*)d_in[5];
  const float* b_out_s    = (const float*)d_in[6];
  const float* ln_out_s_g = (const float*)d_in[7];
  const float* ln_out_s_b = (const float*)d_in[8];
  const float* w_ff_s     = (const float*)d_in[9];
  const float* b_ff_s     = (const float*)d_in[10];
  const float* ln_ff_s_g  = (const float*)d_in[11];
  const float* ln_ff_s_b  = (const float*)d_in[12];
  const float* w_in_t     = (const float*)d_in[13];
  const float* b_in_t     = (const float*)d_in[14];
  const float* alphat_f   = (const float*)d_in[15];
  const float* alphat_b   = (const float*)d_in[16];
  const float* w_out_t    = (const float*)d_in[17];
  const float* b_out_t    = (const float*)d_in[18];
  const float* ln_out_t_g = (const float*)d_in[19];
  const float* ln_out_t_b = (const float*)d_in[20];
  const float* w_ff_t     = (const float*)d_in[21];
  const float* b_ff_t     = (const float*)d_in[22];
  const float* ln_ff_t_g  = (const float*)d_in[23];
  const float* ln_ff_t_b  = (const float*)d_in[24];
  const float* conv_w     = (const float*)d_in[25];
  const float* conv_b     = (const float*)d_in[26];
  const float* bn_g       = (const float*)d_in[27];
  const float* bn_b       = (const float*)d_in[28];
  float* out = (float*)d_out;
  float* ws = (float*)d_ws;

  // Workspace (floats): total 54,525,952 = 218.1 MB.
  float* att4 = ws;
  float* part = ws;                    // 1600*128, live 9-10 (att4 dead)
  float* wT   = ws + 1048576;          // 28672
  float* bnsc = ws + 1080000;          // 128
  float* qk   = ws + 2097152;          // 19,660,800
  float* y2   = ws + 2097152;          // 13,107,200
  float* qkt  = ws + 2097152;          // 26,214,400
  float* z1b  = ws + 2097152;          // 13,107,200
  float* yt   = ws + 28311552;         // 13,107,200
  float* zf   = ws + 41418752;         // 13,107,200
  float* att_s = out;                  // scratch (dead before final)
  float* z2    = out;                  // scratch (dead before final)

  dim3 blk(256);
  // ---- spatial ----
  gemm_k64<96><<<3200, blk, 0, stream>>>(x, w_in_s, b_in_s, qk);
  att_s_kernel<<<128 * 7, blk, 0, stream>>>(qk, alphas, att0s, att_s);
  mix_gemm_s<<<8192, blk, 0, stream>>>(x, att_s, w_out_s, b_out_s, y2);
  lnln_s_kernel<<<3200, blk, 0, stream>>>(y2, x, w_ff_s, b_ff_s, ln_out_s_g, ln_out_s_b,
                                          ln_ff_s_g, ln_ff_s_b, yt);
  // ---- temporal ----
  gemm_k64<128><<<3200, blk, 0, stream>>>(yt, w_in_t, b_in_t, qkt);
  att_t_kernel<<<128 * 8, blk, 0, stream>>>(qkt, alphat_f, alphat_b, att4);
  mix_gemm_t<<<6400, blk, 0, stream>>>(yt, att4, w_out_t, b_out_t, z2);
  lnln_t_kernel<<<8192, blk, 0, stream>>>(z2, yt, w_ff_t, b_ff_t, ln_out_t_g, ln_out_t_b,
                                          ln_ff_t_g, ln_ff_t_b, zf);
  // ---- conv + BN + output ----
  convw_transpose<<<112, blk, 0, stream>>>(conv_w, wT);
  conv_gemm<<<1600, blk, 0, stream>>>(zf, wT, conv_b, z1b, part);
  bn_final<<<64, blk, 0, stream>>>(part, bn_g, bn_b, bnsc);
  final_kernel<<<8192, blk, 0, stream>>>(zf, z1b, bnsc, out);
}

// Round 9
// 2151.815 us; speedup vs baseline: 2.2708x; 1.2063x over previous
//
#include <hip/hip_runtime.h>
#include <math.h>

namespace {

__device__ __forceinline__ float gelu_f(float x) {
  return 0.5f * x * (1.0f + erff(x * 0.7071067811865475f));
}

__device__ __forceinline__ float block_sum(float v, float* red, int tid) {
  red[tid] = v; __syncthreads();
#pragma unroll
  for (int o = 128; o > 0; o >>= 1) {
    if (tid < o) red[tid] += red[tid + o];
    __syncthreads();
  }
  float r = red[0]; __syncthreads();
  return r;
}

// ---------------------------------------------------------------------------
// K=64 GEMM: C[204800 x NC] = A[204800 x 64] @ B[64 x NC] + bias.
// ---------------------------------------------------------------------------
template <int NC>
__launch_bounds__(256, 2)
__global__ void gemm_k64(const float* __restrict__ A, const float* __restrict__ B,
                         const float* __restrict__ bias, float* __restrict__ C) {
  __shared__ float Al[64 * 68];
  __shared__ float Bl[64 * (NC + 4)];
  const int tid = threadIdx.x;
  const int row0 = blockIdx.x * 64;
  for (int i = tid; i < 4096; i += 256)
    Al[(i >> 6) * 68 + (i & 63)] = A[(size_t)(row0 + (i >> 6)) * 64 + (i & 63)];
  for (int i = tid; i < 64 * NC; i += 256) {
    int k = i / NC, c = i - k * NC;
    Bl[k * (NC + 4) + c] = B[i];
  }
  __syncthreads();
  const int ri = tid >> 5, cg = tid & 31;
  if (cg * 4 < NC) {
    float4 acc[8];
    float4 bf = *(const float4*)&bias[cg * 4];
#pragma unroll
    for (int i = 0; i < 8; ++i) acc[i] = bf;
    for (int k0 = 0; k0 < 64; k0 += 4) {
      float4 bv0 = *(const float4*)&Bl[(k0 + 0) * (NC + 4) + cg * 4];
      float4 bv1 = *(const float4*)&Bl[(k0 + 1) * (NC + 4) + cg * 4];
      float4 bv2 = *(const float4*)&Bl[(k0 + 2) * (NC + 4) + cg * 4];
      float4 bv3 = *(const float4*)&Bl[(k0 + 3) * (NC + 4) + cg * 4];
#pragma unroll
      for (int i = 0; i < 8; ++i) {
        float4 av = *(const float4*)&Al[(ri * 8 + i) * 68 + k0];
        acc[i].x += av.x * bv0.x + av.y * bv1.x + av.z * bv2.x + av.w * bv3.x;
        acc[i].y += av.x * bv0.y + av.y * bv1.y + av.z * bv2.y + av.w * bv3.y;
        acc[i].z += av.x * bv0.z + av.y * bv1.z + av.z * bv2.z + av.w * bv3.z;
        acc[i].w += av.x * bv0.w + av.y * bv1.w + av.z * bv2.w + av.w * bv3.w;
      }
    }
#pragma unroll
    for (int i = 0; i < 8; ++i)
      *(float4*)&C[(size_t)(row0 + ri * 8 + i) * NC + cg * 4] = acc[i];
  }
}

// ---------------------------------------------------------------------------
// Generic row-block GEMM: C[rows x 64] = A[rows x KT] @ Bp[KT x 64] + bias.
// Bp is PRE-PERMUTED so K-chunks are contiguous. 128 rows/block, thread =
// 4 rows (rowg+32i) x 8 cols. Per k-quad: 4 A-b128 + 8 B-b128 per 128 FMA.
// ---------------------------------------------------------------------------
template <int KT>
__launch_bounds__(256, 3)
__global__ void gemm_kn(const float* __restrict__ A, const float* __restrict__ Bp,
                        const float* __restrict__ bias, float* __restrict__ C) {
  __shared__ float Al[128 * 68];   // 34.8 KB
  __shared__ float Bl[64 * 68];    // 17.4 KB
  const int tid = threadIdx.x;
  const int r0 = blockIdx.x * 128;
  const int rowg = tid >> 3, colg = tid & 7, c0 = colg * 8;
  float4 acc[4][2];
  {
    float4 b0 = *(const float4*)&bias[c0];
    float4 b1 = *(const float4*)&bias[c0 + 4];
#pragma unroll
    for (int i = 0; i < 4; ++i) { acc[i][0] = b0; acc[i][1] = b1; }
  }
  for (int kc = 0; kc < KT / 64; ++kc) {
    __syncthreads();
    for (int i = tid; i < 8192; i += 256) {
      int rl = i >> 6, k = i & 63;
      Al[rl * 68 + k] = A[(size_t)(r0 + rl) * KT + kc * 64 + k];
    }
    for (int i = tid; i < 4096; i += 256)
      Bl[(i >> 6) * 68 + (i & 63)] = Bp[(size_t)kc * 4096 + i];
    __syncthreads();
    for (int k0 = 0; k0 < 64; k0 += 4) {
      float4 bb[4][2];
#pragma unroll
      for (int k = 0; k < 4; ++k) {
        bb[k][0] = *(const float4*)&Bl[(k0 + k) * 68 + c0];
        bb[k][1] = *(const float4*)&Bl[(k0 + k) * 68 + c0 + 4];
      }
#pragma unroll
      for (int i = 0; i < 4; ++i) {
        float4 av = *(const float4*)&Al[(rowg + 32 * i) * 68 + k0];
#pragma unroll
        for (int h = 0; h < 2; ++h) {
          acc[i][h].x += av.x * bb[0][h].x + av.y * bb[1][h].x + av.z * bb[2][h].x + av.w * bb[3][h].x;
          acc[i][h].y += av.x * bb[0][h].y + av.y * bb[1][h].y + av.z * bb[2][h].y + av.w * bb[3][h].y;
          acc[i][h].z += av.x * bb[0][h].z + av.y * bb[1][h].z + av.z * bb[2][h].z + av.w * bb[3][h].z;
          acc[i][h].w += av.x * bb[0][h].w + av.y * bb[1][h].w + av.z * bb[2][h].w + av.w * bb[3][h].w;
        }
      }
    }
  }
#pragma unroll
  for (int i = 0; i < 4; ++i) {
    *(float4*)&C[(size_t)(r0 + rowg + 32 * i) * 64 + c0] = acc[i][0];
    *(float4*)&C[(size_t)(r0 + rowg + 32 * i) * 64 + c0 + 4] = acc[i][1];
  }
}

// wp_s[(s*64+c)*64+c'] = w_out_s[(c*3+s)*64+c']
__global__ void permute_ws_k(const float* __restrict__ w, float* __restrict__ wp) {
  int i = blockIdx.x * 256 + threadIdx.x;
  if (i < 12288) {
    int row = i >> 6, cc = i & 63;
    int s = row >> 6, c = row & 63;
    wp[i] = w[(c * 3 + s) * 64 + cc];
  }
}

// wp_t[(dir*128+s*64+c)*64+c'] = w_out_t[(dir*128+c*2+s)*64+c']
__global__ void permute_wt_k(const float* __restrict__ w, float* __restrict__ wp) {
  int i = blockIdx.x * 256 + threadIdx.x;
  if (i < 16384) {
    int row = i >> 6, cc = i & 63;
    int dir = row >> 7, r2 = row & 127, s = r2 >> 6, c = r2 & 63;
    wp[i] = w[(dir * 128 + c * 2 + s) * 64 + cc];
  }
}

// ---------------------------------------------------------------------------
// Spatial attention scores. Block = (n, u-quad).
// ---------------------------------------------------------------------------
__global__ void att_s_kernel(const float* __restrict__ qk, const float* __restrict__ alphas,
                             const float* __restrict__ att0, float* __restrict__ att) {
  __shared__ float qs[4 * 3072];
  __shared__ float ks[3072];
  const int b = blockIdx.x, tid = threadIdx.x;
  const int n = b / 7, ug = b % 7;
  const int u0 = ug * 4;
  const int nu = (25 - u0 < 4) ? (25 - u0) : 4;
  for (int i = tid; i < nu * 3072; i += 256) {
    int ul = i / 3072, r = i - ul * 3072;
    int s = r >> 10, idx = r & 1023, t = idx >> 4, c = idx & 15;
    qs[i] = qk[(size_t)(n * 25 + u0 + ul) * 6144 + t * 96 + c * 6 + s];
  }
  const int ui = tid >> 6, l = tid & 63;
  const int u = u0 + ui;
  const float a0 = alphas[0], a1 = alphas[1], a2 = alphas[2];
  for (int v = 0; v < 25; ++v) {
    __syncthreads();
    for (int i = tid; i < 3072; i += 256) {
      int s = i >> 10, idx = i & 1023, t = idx >> 4, c = idx & 15;
      ks[i] = qk[(size_t)(n * 25 + v) * 6144 + t * 96 + c * 6 + 3 + s];
    }
    __syncthreads();
    if (u < 25) {
      float s0 = 0.f, s1 = 0.f, s2 = 0.f;
      for (int idx = l; idx < 1024; idx += 64) {
        s0 += qs[ui * 3072 + idx] * ks[idx];
        s1 += qs[ui * 3072 + 1024 + idx] * ks[1024 + idx];
        s2 += qs[ui * 3072 + 2048 + idx] * ks[2048 + idx];
      }
#pragma unroll
      for (int o = 32; o > 0; o >>= 1) {
        s0 += __shfl_down(s0, o);
        s1 += __shfl_down(s1, o);
        s2 += __shfl_down(s2, o);
      }
      if (l == 0) {
        float* dst = &att[(size_t)((n * 25 + u) * 25 + v) * 3];
        const float* ap = &att0[(u * 25 + v) * 3];
        dst[0] = tanhf(s0 * (1.f / 1024.f)) * a0 + ap[0];
        dst[1] = tanhf(s1 * (1.f / 1024.f)) * a1 + ap[1];
        dst[2] = tanhf(s2 * (1.f / 1024.f)) * a2 + ap[2];
      }
    }
  }
}

// ---------------------------------------------------------------------------
// Spatial mix, materializing y1[(n,v,t), s*64+c] (GEMM-friendly K-order).
// Block (n, t-quad); thread (v, c-oct) holds acc[4t][3s][8c] in registers.
// ---------------------------------------------------------------------------
__launch_bounds__(256, 3)
__global__ void mix_s_y1(const float* __restrict__ x, const float* __restrict__ att,
                         float* __restrict__ y1) {
  __shared__ float ap[625 * 4];     // [v][u][4] packed att
  __shared__ float xs[4 * 25 * 68]; // [tl][u][c]
  const int b = blockIdx.x, tid = threadIdx.x;
  const int n = b >> 4, tq = b & 15;
  for (int i = tid; i < 1875; i += 256) {
    int u = i / 75, rem = i - u * 75, v = rem / 3, s = rem - v * 3;
    ap[(v * 25 + u) * 4 + s] = att[(size_t)n * 1875 + i];
  }
  for (int i = tid; i < 6400; i += 256) {
    int tl = i / 1600, r = i - tl * 1600, u = r >> 6, c = r & 63;
    xs[(tl * 25 + u) * 68 + c] = x[(size_t)((n * 25 + u) * 64 + tq * 4 + tl) * 64 + c];
  }
  __syncthreads();
  if (tid < 200) {
    const int v = tid >> 3, c0 = (tid & 7) * 8;
    float4 acc[4][3][2];
#pragma unroll
    for (int tl = 0; tl < 4; ++tl)
#pragma unroll
      for (int s = 0; s < 3; ++s) {
        acc[tl][s][0] = make_float4(0.f, 0.f, 0.f, 0.f);
        acc[tl][s][1] = make_float4(0.f, 0.f, 0.f, 0.f);
      }
    for (int u = 0; u < 25; ++u) {
      float4 a = *(const float4*)&ap[(v * 25 + u) * 4];
#pragma unroll
      for (int tl = 0; tl < 4; ++tl) {
        const float* xp = &xs[(tl * 25 + u) * 68 + c0];
        float4 x0 = *(const float4*)&xp[0];
        float4 x1 = *(const float4*)&xp[4];
#define MIXFMA(S, AS)                                                        \
  acc[tl][S][0].x += x0.x * AS; acc[tl][S][0].y += x0.y * AS;                \
  acc[tl][S][0].z += x0.z * AS; acc[tl][S][0].w += x0.w * AS;                \
  acc[tl][S][1].x += x1.x * AS; acc[tl][S][1].y += x1.y * AS;                \
  acc[tl][S][1].z += x1.z * AS; acc[tl][S][1].w += x1.w * AS
        MIXFMA(0, a.x);
        MIXFMA(1, a.y);
        MIXFMA(2, a.z);
#undef MIXFMA
      }
    }
#pragma unroll
    for (int tl = 0; tl < 4; ++tl) {
      float* yp = &y1[(size_t)((n * 25 + v) * 64 + tq * 4 + tl) * 192];
#pragma unroll
      for (int s = 0; s < 3; ++s) {
        *(float4*)&yp[s * 64 + c0] = acc[tl][s][0];
        *(float4*)&yp[s * 64 + c0 + 4] = acc[tl][s][1];
      }
    }
  }
}

// ---------------------------------------------------------------------------
// Fused LN -> gelu(x+.) -> @w_ff -> LN -> gelu(x+.) (spatial). Block (n,v).
// ---------------------------------------------------------------------------
__global__ void lnln_s_kernel(const float* __restrict__ y2, const float* __restrict__ x,
                              const float* __restrict__ wff, const float* __restrict__ bff,
                              const float* __restrict__ g1, const float* __restrict__ b1,
                              const float* __restrict__ g2, const float* __restrict__ b2,
                              float* __restrict__ yt) {
  __shared__ float ya[64 * 66];
  __shared__ float wl[64 * 68];
  __shared__ float y6l[64 * 68];
  __shared__ float red[256];
  const int g = blockIdx.x, tid = threadIdx.x;
  const int n = g / 25, v = g % 25;
  const size_t base = (size_t)g * 4096;
  float s = 0.f;
  for (int i = tid; i < 4096; i += 256) {
    float val = y2[base + i];
    ya[(i >> 6) * 66 + (i & 63)] = val;
    s += val;
  }
  for (int i = tid; i < 4096; i += 256) wl[(i >> 6) * 68 + (i & 63)] = wff[i];
  float mean = block_sum(s, red, tid) * (1.f / 4096.f);
  float sq = 0.f;
  for (int i = tid; i < 4096; i += 256) {
    float d = ya[(i >> 6) * 66 + (i & 63)] - mean;
    sq += d * d;
  }
  float inv = rsqrtf(block_sum(sq, red, tid) * (1.f / 4096.f) + 1e-5f);
  for (int i = tid; i < 4096; i += 256) {
    int o = (i >> 6) * 66 + (i & 63);
    ya[o] = gelu_f(x[base + i] + (ya[o] - mean) * inv * g1[i] + b1[i]);
  }
  __syncthreads();
  const int ri = tid >> 4, ci = tid & 15;
  {
    float4 bf = *(const float4*)&bff[ci * 4];
    float4 acc[4];
#pragma unroll
    for (int i = 0; i < 4; ++i) acc[i] = bf;
    for (int k = 0; k < 64; ++k) {
      float4 wv = *(const float4*)&wl[k * 68 + ci * 4];
#pragma unroll
      for (int i = 0; i < 4; ++i) {
        float av = ya[(ri + 16 * i) * 66 + k];
        acc[i].x += av * wv.x; acc[i].y += av * wv.y;
        acc[i].z += av * wv.z; acc[i].w += av * wv.w;
      }
    }
#pragma unroll
    for (int i = 0; i < 4; ++i)
      *(float4*)&y6l[(ri + 16 * i) * 68 + ci * 4] = acc[i];
  }
  __syncthreads();
  float s2 = 0.f;
  for (int i = tid; i < 4096; i += 256) s2 += y6l[(i >> 6) * 68 + (i & 63)];
  float mean2 = block_sum(s2, red, tid) * (1.f / 4096.f);
  float sq2 = 0.f;
  for (int i = tid; i < 4096; i += 256) {
    float d = y6l[(i >> 6) * 68 + (i & 63)] - mean2;
    sq2 += d * d;
  }
  float inv2 = rsqrtf(block_sum(sq2, red, tid) * (1.f / 4096.f) + 1e-5f);
  for (int i = tid; i < 4096; i += 256) {
    int t = i >> 6, c = i & 63;
    yt[(size_t)((n * 64 + t) * 25 + v) * 64 + c] =
        gelu_f(x[base + i] + (y6l[t * 68 + c] - mean2) * inv2 * g2[i] + b2[i]);
  }
}

// ---------------------------------------------------------------------------
// Temporal attention scores. Block = (n, t-oct).
// ---------------------------------------------------------------------------
__global__ void att_t_kernel(const float* __restrict__ qkt, const float* __restrict__ af_al,
                             const float* __restrict__ ab_al, float* __restrict__ att4) {
  __shared__ float qs[8 * 1600];
  __shared__ float ks[1600];
  const int b = blockIdx.x, tid = threadIdx.x;
  const int n = b >> 3, to = b & 7;
  for (int i = tid; i < 8 * 1600; i += 256) {
    int tt = i / 1600, r = i - tt * 1600;
    int pair = r >> 2, j = r & 3, v = pair >> 4, c = pair & 15;
    qs[i] = qkt[(size_t)((n * 64 + to * 8 + tt) * 25 + v) * 128 + c * 8 + j];
  }
  const int tt = tid >> 5, l = tid & 31;
  const int t = to * 8 + tt;
  const float af0 = af_al[0], af1 = af_al[1], ab0 = ab_al[0], ab1 = ab_al[1];
  for (int q = 0; q < 64; ++q) {
    __syncthreads();
    for (int i = tid; i < 1600; i += 256) {
      int pair = i >> 2, j = i & 3, v = pair >> 4, c = pair & 15;
      ks[i] = qkt[(size_t)((n * 64 + q) * 25 + v) * 128 + c * 8 + 4 + j];
    }
    __syncthreads();
    float f0 = 0.f, f1 = 0.f, b0 = 0.f, b1 = 0.f;
    for (int idx = l; idx < 400; idx += 32) {
      float4 q4 = *(const float4*)&qs[tt * 1600 + idx * 4];
      float4 k4 = *(const float4*)&ks[idx * 4];
      f0 += q4.x * k4.x; f1 += q4.y * k4.y;
      b0 += q4.z * k4.z; b1 += q4.w * k4.w;
    }
#pragma unroll
    for (int o = 16; o > 0; o >>= 1) {
      f0 += __shfl_down(f0, o, 32); f1 += __shfl_down(f1, o, 32);
      b0 += __shfl_down(b0, o, 32); b1 += __shfl_down(b1, o, 32);
    }
    if (l == 0) {
      float mf = (q <= t) ? 1.f : 0.f;
      float mb = (q >= t) ? 1.f : 0.f;
      size_t o4 = ((size_t)(n * 4 + 0) * 64 + t) * 64 + q;
      att4[o4]            = tanhf(f0 * (1.f / 400.f)) * af0 * mf;
      att4[o4 + 4096]     = tanhf(f1 * (1.f / 400.f)) * af1 * mf;
      att4[o4 + 2 * 4096] = tanhf(b0 * (1.f / 400.f)) * ab0 * mb;
      att4[o4 + 3 * 4096] = tanhf(b1 * (1.f / 400.f)) * ab1 * mb;
    }
  }
}

// ---------------------------------------------------------------------------
// Temporal mix, materializing zv[(nl,q,v), dir*128+s*64+c] for one n-half.
// ---------------------------------------------------------------------------
__launch_bounds__(256, 2)
__global__ void mix_t_zv(const float* __restrict__ yt, const float* __restrict__ att4,
                         float* __restrict__ zv, int n0) {
  __shared__ float smem[12288];
  float* as4 = smem;
  float* ys = smem + 8192;
  const int b = blockIdx.x, tid = threadIdx.x;
  const int nl = b / 50, r = b % 50;
  const int n = n0 + nl;
  const int v = r >> 1, qh = r & 1;
  const int q0b = qh * 32;
  for (int i = tid; i < 8192; i += 256) {
    int sdi = i >> 11, t = (i >> 5) & 63, qq = i & 31;
    as4[i] = att4[((size_t)(n * 4 + sdi) * 64 + t) * 64 + q0b + qq];
  }
  for (int i = tid; i < 4096; i += 256) {
    int t = i >> 6, c = i & 63;
    ys[i] = yt[(size_t)((n * 64 + t) * 25 + v) * 64 + c];
  }
  __syncthreads();
  const int qg = tid >> 4, cg = tid & 15;
  const int q0 = qg * 2, c0 = cg * 4;
  float4 a00 = {0,0,0,0}, a01 = {0,0,0,0}, a10 = {0,0,0,0}, a11 = {0,0,0,0};
  float4 a20 = {0,0,0,0}, a21 = {0,0,0,0}, a30 = {0,0,0,0}, a31 = {0,0,0,0};
  for (int t = 0; t < 64; ++t) {
    float4 bv = *(const float4*)&ys[t * 64 + c0];
    float2 av0 = *(const float2*)&as4[(0 * 64 + t) * 32 + q0];
    float2 av1 = *(const float2*)&as4[(1 * 64 + t) * 32 + q0];
    float2 av2 = *(const float2*)&as4[(2 * 64 + t) * 32 + q0];
    float2 av3 = *(const float2*)&as4[(3 * 64 + t) * 32 + q0];
#define FMA4S(A, S) A.x += bv.x * (S); A.y += bv.y * (S); A.z += bv.z * (S); A.w += bv.w * (S)
    FMA4S(a00, av0.x); FMA4S(a01, av0.y);
    FMA4S(a10, av1.x); FMA4S(a11, av1.y);
    FMA4S(a20, av2.x); FMA4S(a21, av2.y);
    FMA4S(a30, av3.x); FMA4S(a31, av3.y);
#undef FMA4S
  }
  // zv row = (nl*64 + q0b + q)*25 + v; col = (sdi>>1)*128 + (sdi&1)*64 + c
#define STORE_ZV(A, SDI, QI)                                                  \
  *(float4*)&zv[(size_t)((nl * 64 + q0b + q0 + (QI)) * 25 + v) * 256 +        \
                ((SDI) >> 1) * 128 + ((SDI) & 1) * 64 + c0] = A
  STORE_ZV(a00, 0, 0); STORE_ZV(a01, 0, 1);
  STORE_ZV(a10, 1, 0); STORE_ZV(a11, 1, 1);
  STORE_ZV(a20, 2, 0); STORE_ZV(a21, 2, 1);
  STORE_ZV(a30, 3, 0); STORE_ZV(a31, 3, 1);
#undef STORE_ZV
}

// ---------------------------------------------------------------------------
// Fused LN -> gelu(y+.) -> @w_ff_t -> LN -> gelu(y+.) (temporal). Block (n,q).
// ---------------------------------------------------------------------------
__global__ void lnln_t_kernel(const float* __restrict__ z2, const float* __restrict__ ytr,
                              const float* __restrict__ wff, const float* __restrict__ bff,
                              const float* __restrict__ g1, const float* __restrict__ b1,
                              const float* __restrict__ g2, const float* __restrict__ b2,
                              float* __restrict__ zf) {
  __shared__ float za[25 * 66];
  __shared__ float yts[25 * 66];
  __shared__ float wl[64 * 68];
  __shared__ float z6l[25 * 68];
  __shared__ float red[256];
  const int g = blockIdx.x, tid = threadIdx.x;
  const size_t base = (size_t)g * 1600;
  float s = 0.f;
  for (int i = tid; i < 1600; i += 256) {
    float val = z2[base + i];
    za[(i >> 6) * 66 + (i & 63)] = val;
    yts[(i >> 6) * 66 + (i & 63)] = ytr[base + i];
    s += val;
  }
  for (int i = tid; i < 4096; i += 256) wl[(i >> 6) * 68 + (i & 63)] = wff[i];
  float mean = block_sum(s, red, tid) * (1.f / 1600.f);
  float sq = 0.f;
  for (int i = tid; i < 1600; i += 256) {
    float d = za[(i >> 6) * 66 + (i & 63)] - mean;
    sq += d * d;
  }
  float inv = rsqrtf(block_sum(sq, red, tid) * (1.f / 1600.f) + 1e-5f);
  for (int i = tid; i < 1600; i += 256) {
    int o = (i >> 6) * 66 + (i & 63);
    za[o] = gelu_f(yts[o] + (za[o] - mean) * inv * g1[i] + b1[i]);
  }
  __syncthreads();
  for (int slot = tid; slot < 400; slot += 256) {
    int v = slot >> 4, cq = slot & 15;
    float4 acc = *(const float4*)&bff[cq * 4];
    for (int k = 0; k < 64; ++k) {
      float av = za[v * 66 + k];
      float4 wv = *(const float4*)&wl[k * 68 + cq * 4];
      acc.x += av * wv.x; acc.y += av * wv.y; acc.z += av * wv.z; acc.w += av * wv.w;
    }
    *(float4*)&z6l[v * 68 + cq * 4] = acc;
  }
  __syncthreads();
  float s2 = 0.f;
  for (int i = tid; i < 1600; i += 256) s2 += z6l[(i >> 6) * 68 + (i & 63)];
  float mean2 = block_sum(s2, red, tid) * (1.f / 1600.f);
  float sq2 = 0.f;
  for (int i = tid; i < 1600; i += 256) {
    float d = z6l[(i >> 6) * 68 + (i & 63)] - mean2;
    sq2 += d * d;
  }
  float inv2 = rsqrtf(block_sum(sq2, red, tid) * (1.f / 1600.f) + 1e-5f);
  for (int i = tid; i < 1600; i += 256) {
    int o = (i >> 6) * 68 + (i & 63);
    zf[base + i] = gelu_f(yts[(i >> 6) * 66 + (i & 63)] + (z6l[o] - mean2) * inv2 * g2[i] + b2[i]);
  }
}

// conv weight transpose: wT[(dt*64+c)*64+c'] = w[(c'*64+c)*7+dt]
__global__ void convw_transpose(const float* __restrict__ w, float* __restrict__ wT) {
  int idx = blockIdx.x * 256 + threadIdx.x;
  if (idx < 64 * 64 * 7) {
    int dt = idx % 7, c = (idx / 7) % 64, cp = idx / 448;
    wT[(dt * 64 + c) * 64 + cp] = w[idx];
  }
}

// ---------------------------------------------------------------------------
// Conv as K=448 GEMM with 7 t-shifted A-tiles.
// ---------------------------------------------------------------------------
__launch_bounds__(256, 2)
__global__ void conv_gemm(const float* __restrict__ zf, const float* __restrict__ wT,
                          const float* __restrict__ cb, float* __restrict__ z1,
                          float* __restrict__ part) {
  __shared__ float Al[128 * 68];
  __shared__ float Bl[64 * 68];
  const int tid = threadIdx.x;
  const int r0 = blockIdx.x * 128;
  const int ri = tid >> 4;
  const int cg = tid & 15;
  float4 acc[8];
  float4 bf = *(const float4*)&cb[cg * 4];
#pragma unroll
  for (int i = 0; i < 8; ++i) acc[i] = bf;
  for (int dt = 0; dt < 7; ++dt) {
    __syncthreads();
    for (int i = tid; i < 8192; i += 256) {
      int rl = i >> 6, c = i & 63;
      int grow = r0 + rl;
      int t = (grow % 1600) / 25;
      int tt = t + dt - 3;
      float val = 0.f;
      if (tt >= 0 && tt < 64)
        val = zf[(size_t)(grow + (dt - 3) * 25) * 64 + c];
      Al[rl * 68 + c] = val;
    }
    for (int i = tid; i < 4096; i += 256)
      Bl[(i >> 6) * 68 + (i & 63)] = wT[dt * 4096 + i];
    __syncthreads();
    for (int k0 = 0; k0 < 64; k0 += 4) {
      float4 bv0 = *(const float4*)&Bl[(k0 + 0) * 68 + cg * 4];
      float4 bv1 = *(const float4*)&Bl[(k0 + 1) * 68 + cg * 4];
      float4 bv2 = *(const float4*)&Bl[(k0 + 2) * 68 + cg * 4];
      float4 bv3 = *(const float4*)&Bl[(k0 + 3) * 68 + cg * 4];
#pragma unroll
      for (int i = 0; i < 8; ++i) {
        float4 av = *(const float4*)&Al[(ri + 16 * i) * 68 + k0];
        acc[i].x += av.x * bv0.x + av.y * bv1.x + av.z * bv2.x + av.w * bv3.x;
        acc[i].y += av.x * bv0.y + av.y * bv1.y + av.z * bv2.y + av.w * bv3.y;
        acc[i].z += av.x * bv0.z + av.y * bv1.z + av.z * bv2.z + av.w * bv3.z;
        acc[i].w += av.x * bv0.w + av.y * bv1.w + av.z * bv2.w + av.w * bv3.w;
      }
    }
  }
  float4 psum = {0, 0, 0, 0}, psq = {0, 0, 0, 0};
#pragma unroll
  for (int i = 0; i < 8; ++i) {
    *(float4*)&z1[(size_t)(r0 + ri + 16 * i) * 64 + cg * 4] = acc[i];
    psum.x += acc[i].x; psum.y += acc[i].y; psum.z += acc[i].z; psum.w += acc[i].w;
    psq.x += acc[i].x * acc[i].x; psq.y += acc[i].y * acc[i].y;
    psq.z += acc[i].z * acc[i].z; psq.w += acc[i].w * acc[i].w;
  }
  __syncthreads();
  *(float4*)&Al[ri * 68 + cg * 4] = psum;
  *(float4*)&Bl[ri * 68 + cg * 4] = psq;
  __syncthreads();
  if (tid < 64) {
    float s = 0.f, q = 0.f;
    for (int r = 0; r < 16; ++r) {
      s += Al[r * 68 + tid];
      q += Bl[r * 68 + tid];
    }
    part[(size_t)blockIdx.x * 128 + tid] = s;
    part[(size_t)blockIdx.x * 128 + 64 + tid] = q;
  }
}

__global__ void bn_final(const float* __restrict__ part, const float* __restrict__ g,
                         const float* __restrict__ bb, float* __restrict__ sc) {
  __shared__ float red[256], red2[256];
  const int c = blockIdx.x;
  const int tid = threadIdx.x;
  float s = 0.f, q = 0.f;
  for (int i = tid; i < 1600; i += 256) {
    s += part[(size_t)i * 128 + c];
    q += part[(size_t)i * 128 + 64 + c];
  }
  red[tid] = s;
  red2[tid] = q;
  __syncthreads();
#pragma unroll
  for (int o = 128; o > 0; o >>= 1) {
    if (tid < o) { red[tid] += red[tid + o]; red2[tid] += red2[tid + o]; }
    __syncthreads();
  }
  if (tid == 0) {
    const float M = 204800.f;
    float mean = red[0] / M;
    float var = red2[0] / M - mean * mean;
    float scale = g[c] * rsqrtf(var + 1e-5f);
    sc[c] = scale;
    sc[64 + c] = bb[c] - mean * scale;
  }
}

__global__ void final_kernel(const float* __restrict__ zf, const float* __restrict__ z1,
                             const float* __restrict__ sc, float* __restrict__ out) {
  const int b = blockIdx.x;
  const int n = b / 64, t = b % 64;
  const int tid = threadIdx.x;
  const size_t base = (size_t)(n * 64 + t) * 1600;
  for (int i = tid; i < 1600; i += 256) {
    int v = i >> 6, c = i & 63;
    float val = zf[base + i] + z1[base + i] * sc[c] + sc[64 + c];
    out[(size_t)((n * 25 + v) * 64 + t) * 64 + c] = gelu_f(val);
  }
}

}  // namespace

extern "C" void kernel_launch(void* const* d_in, const int* in_sizes, int n_in,
                              void* d_out, int out_size, void* d_ws, size_t ws_size,
                              hipStream_t stream) {
  (void)in_sizes; (void)n_in; (void)out_size; (void)ws_size;
  const float* x          = (const float*)d_in[0];
  const float* w_in_s     = (const float*)d_in[1];
  const float* b_in_s     = (const float*)d_in[2];
  const float* alphas     = (const float*)d_in[3];
  const float* att0s      = (const float*)d_in[4];
  const float* w_out_s    = (const float*)d_in[5];
  const float* b_out_s    = (const float*)d_in[6];
  const float* ln_out_s_g = (const float*)d_in[7];
  const float* ln_out_s_b = (const float*)d_in[8];
  const float* w_ff_s     = (const float*)d_in[9];
  const float* b_ff_s     = (const float*)d_in[10];
  const float* ln_ff_s_g  = (const float*)d_in[11];
  const float* ln_ff_s_b  = (const float*)d_in[12];
  const float* w_in_t     = (const float*)d_in[13];
  const float* b_in_t     = (const float*)d_in[14];
  const float* alphat_f   = (const float*)d_in[15];
  const float* alphat_b   = (const float*)d_in[16];
  const float* w_out_t    = (const float*)d_in[17];
  const float* b_out_t    = (const float*)d_in[18];
  const float* ln_out_t_g = (const float*)d_in[19];
  const float* ln_out_t_b = (const float*)d_in[20];
  const float* w_ff_t     = (const float*)d_in[21];
  const float* b_ff_t     = (const float*)d_in[22];
  const float* ln_ff_t_g  = (const float*)d_in[23];
  const float* ln_ff_t_b  = (const float*)d_in[24];
  const float* conv_w     = (const float*)d_in[25];
  const float* conv_b     = (const float*)d_in[26];
  const float* bn_g       = (const float*)d_in[27];
  const float* bn_b       = (const float*)d_in[28];
  float* out = (float*)d_out;
  float* ws = (float*)d_ws;

  // -------------------------------------------------------------------------
  // Workspace (floats): total 54,583,424 = 218.3 MB.
  // ROUND-8 BUGFIX: att4 spans [0, 2,097,152) (128n x 4sdi x 64 x 64 = 2.1M
  // floats, NOT 1.05M as round-6 assumed). Weight buffers (wT/bnsc/wp_s/wp_t)
  // previously sat at 1.05-1.14M and were clobbered by att_t_kernel's att4
  // write -> gemm_kn<256> and conv_gemm read garbage (absmax 7.6). They now
  // live ABOVE zf, outside every big buffer's range.
  //  [0, 2.10M):        att4 (att_t..mix_t) -> part[0..204,800) (conv..bn)
  //  [2.10M, 28.31M):   qk -> qkt -> zv(per half) -> z1b
  //  [2.10M, 41.42M):   y1 (mix_s_y1..gemm_kn<192> only; dead before yt)
  //  [28.31M, 41.42M):  yt (lnln_s..lnln_t)
  //  [41.42M, 54.53M):  zf (lnln_t..final)
  //  [54.53M, 54.58M):  wT, bnsc, wp_s, wp_t (written first, never clobbered)
  //  d_out: att_s -> y2 -> z2 (all dead before final_kernel)
  // -------------------------------------------------------------------------
  float* att4 = ws;
  float* part = ws;
  float* qk   = ws + 2097152;          // 19.66M
  float* y1   = ws + 2097152;          // 39.32M, ends 41,418,752
  float* qkt  = ws + 2097152;          // 26.21M
  float* zv   = ws + 2097152;          // 26.21M per half, ends 28,311,552
  float* z1b  = ws + 2097152;          // 13.1M
  float* yt   = ws + 28311552;         // 13.1M
  float* zf   = ws + 41418752;         // 13.1M, ends 54,525,952
  float* wT   = ws + 54525952;         // 28,672
  float* bnsc = ws + 54554624;         // 128
  float* wp_s = ws + 54554752;         // 12,288
  float* wp_t = ws + 54567040;         // 16,384, ends 54,583,424
  float* att_s = out;
  float* y2    = out;
  float* z2    = out;

  dim3 blk(256);
  // ---- weight prep (targets now outside att4's range) ----
  permute_ws_k<<<48, blk, 0, stream>>>(w_out_s, wp_s);
  permute_wt_k<<<64, blk, 0, stream>>>(w_out_t, wp_t);
  convw_transpose<<<112, blk, 0, stream>>>(conv_w, wT);
  // ---- spatial ----
  gemm_k64<96><<<3200, blk, 0, stream>>>(x, w_in_s, b_in_s, qk);
  att_s_kernel<<<128 * 7, blk, 0, stream>>>(qk, alphas, att0s, att_s);
  mix_s_y1<<<2048, blk, 0, stream>>>(x, att_s, y1);
  gemm_kn<192><<<1600, blk, 0, stream>>>(y1, wp_s, b_out_s, y2);
  lnln_s_kernel<<<3200, blk, 0, stream>>>(y2, x, w_ff_s, b_ff_s, ln_out_s_g, ln_out_s_b,
                                          ln_ff_s_g, ln_ff_s_b, yt);
  // ---- temporal ----
  gemm_k64<128><<<3200, blk, 0, stream>>>(yt, w_in_t, b_in_t, qkt);
  att_t_kernel<<<128 * 8, blk, 0, stream>>>(qkt, alphat_f, alphat_b, att4);
  for (int h = 0; h < 2; ++h) {
    mix_t_zv<<<3200, blk, 0, stream>>>(yt, att4, zv, h * 64);
    gemm_kn<256><<<800, blk, 0, stream>>>(zv, wp_t, b_out_t, z2 + (size_t)h * 6553600);
  }
  lnln_t_kernel<<<8192, blk, 0, stream>>>(z2, yt, w_ff_t, b_ff_t, ln_out_t_g, ln_out_t_b,
                                          ln_ff_t_g, ln_ff_t_b, zf);
  // ---- conv + BN + output ----
  conv_gemm<<<1600, blk, 0, stream>>>(zf, wT, conv_b, z1b, part);
  bn_final<<<64, blk, 0, stream>>>(part, bn_g, bn_b, bnsc);
  final_kernel<<<8192, blk, 0, stream>>>(zf, z1b, bnsc, out);
}